// Round 15
// baseline (879.694 us; speedup 1.0000x reference)
//
#include <hip/hip_runtime.h>
#include <hip/hip_fp16.h>

// ---------------------------------------------------------------------------
// GATv2 3-layer GNN encoder. N=50000 nodes, E=800000 edges, dims 128.
// CSR build + degree-sort + fp16 edge-stream permute (once); per layer:
// [prep_w (+We^T), MFMA dual GEMM (xlh fp16-interleaved + xr fp32), fused
// layer: per 16-edge tile the wave computes eproj = ea@We with 8 MFMAs
// (f16, fp32-acc), then score/softmax/aggregate/LN on the VALU].
// fused: GRID-STRIDE node loop -- We^T/att fragments loaded once per wave,
// amortized over ~12 nodes (avg degree 16 means setup dominated per-node).
// ---------------------------------------------------------------------------

typedef __attribute__((ext_vector_type(8))) short bf16x8;
typedef __attribute__((ext_vector_type(4))) float f32x4;
typedef __fp16 h2 __attribute__((ext_vector_type(2)));
typedef __fp16 h8 __attribute__((ext_vector_type(8)));

__device__ inline ushort f2bf(float f) {
  unsigned u = __float_as_uint(f);
  u += 0x7FFF + ((u >> 16) & 1);
  return (ushort)(u >> 16);
}

__device__ inline ushort f2h(float f) {
  __half h = __float2half(f);
  return *(ushort*)&h;
}

__device__ inline uint pk2(float a, float b) {
#if __has_builtin(__builtin_amdgcn_cvt_pkrtz)
  h2 r = __builtin_amdgcn_cvt_pkrtz(a, b);
  return *(uint*)&r;
#else
  return (uint)f2h(a) | ((uint)f2h(b) << 16);
#endif
}

__device__ inline uint swz_add(uint p, int o) {  // packed-f16 butterfly step
  int q = __shfl_xor(*(int*)&p, o);
  __half2 r = __hadd2(*(__half2*)&p, *(__half2*)&q);
  return *(uint*)&r;
}

// ---------------- CSR build ----------------

__global__ __launch_bounds__(256) void hist_kernel(const int* __restrict__ dst,
                                                   int* __restrict__ deg, int nE) {
  int i = blockIdx.x * 256 + threadIdx.x;
  if (i < nE) atomicAdd(&deg[dst[i]], 1);
}

__global__ __launch_bounds__(1024) void scan_blocks(const int* __restrict__ deg,
                                                    int* __restrict__ rowptr,
                                                    int* __restrict__ bsum, int n) {
  __shared__ int wsum[16];
  __shared__ int wbase[16];
  int tid = threadIdx.x, wid = tid >> 6, lane = tid & 63;
  int i = blockIdx.x * 1024 + tid;
  int v = (i < n) ? deg[i] : 0;
#pragma unroll
  for (int o = 1; o < 64; o <<= 1) {
    int t = __shfl_up(v, o);
    if (lane >= o) v += t;
  }
  if (lane == 63) wsum[wid] = v;
  __syncthreads();
  if (tid < 16) {
    int s = wsum[tid];
#pragma unroll
    for (int o = 1; o < 16; o <<= 1) {
      int t = __shfl_up(s, o);
      if (tid >= o) s += t;
    }
    wbase[tid] = s;
  }
  __syncthreads();
  int base = (wid > 0) ? wbase[wid - 1] : 0;
  if (i < n) rowptr[i + 1] = base + v;
  if (tid == 1023) bsum[blockIdx.x] = wbase[15];
}

__global__ __launch_bounds__(64) void scan_carry(int* __restrict__ bsum, int nb) {
  int lane = threadIdx.x;
  int carry = 0;
  for (int base = 0; base < nb; base += 64) {
    int i = base + lane;
    int v = (i < nb) ? bsum[i] : 0;
    int inc = v;
#pragma unroll
    for (int o = 1; o < 64; o <<= 1) {
      int t = __shfl_up(inc, o);
      if (lane >= o) inc += t;
    }
    if (i < nb) bsum[i] = carry + inc - v;
    carry += __shfl(inc, 63);
  }
}

__global__ __launch_bounds__(1024) void scan_apply(int* __restrict__ rowptr,
                                                   const int* __restrict__ bsum, int n) {
  int i = blockIdx.x * 1024 + threadIdx.x;
  if (i < n) rowptr[i + 1] += bsum[blockIdx.x];
  if (i == 0) rowptr[0] = 0;
}

__global__ __launch_bounds__(256) void scatter_kernel(const int* __restrict__ dst,
                                                      const int* __restrict__ rowptr,
                                                      int* __restrict__ cnt,
                                                      int* __restrict__ eperm, int nE) {
  int i = blockIdx.x * 256 + threadIdx.x;
  if (i < nE) {
    int d = dst[i];
    int p = atomicAdd(&cnt[d], 1);
    eperm[rowptr[d] + p] = i;
  }
}

__global__ __launch_bounds__(256) void deg_hist(const int* __restrict__ rowptr,
                                                int* __restrict__ dh, int nN) {
  int i = blockIdx.x * 256 + threadIdx.x;
  if (i < nN) {
    int dg = min(rowptr[i + 1] - rowptr[i], 255);
    atomicAdd(&dh[dg], 1);
  }
}

__global__ __launch_bounds__(256) void deg_scan(const int* __restrict__ dh,
                                                int* __restrict__ dbase) {
  __shared__ int s[256];
  int t = threadIdx.x;
  s[t] = dh[t];
  __syncthreads();
  for (int ofs = 1; ofs < 256; ofs <<= 1) {
    int v = (t >= ofs) ? s[t - ofs] : 0;
    __syncthreads();
    s[t] += v;
    __syncthreads();
  }
  dbase[t] = s[255] - s[t];
}

__global__ __launch_bounds__(256) void deg_scatter(const int* __restrict__ rowptr,
                                                   const int* __restrict__ dbase,
                                                   int* __restrict__ dcnt,
                                                   int* __restrict__ nodeorder, int nN) {
  int i = blockIdx.x * 256 + threadIdx.x;
  if (i < nN) {
    int dg = min(rowptr[i + 1] - rowptr[i], 255);
    int p = atomicAdd(&dcnt[dg], 1);
    nodeorder[dbase[dg] + p] = i;
  }
}

// ---------------- edge stream prep ----------------

__global__ __launch_bounds__(256) void convert_ea(const float* __restrict__ ea,
                                                  ushort* __restrict__ tmp, int n8) {
  int i = blockIdx.x * 256 + threadIdx.x;
  if (i < n8) {
    float4 a = ((const float4*)ea)[i * 2];
    float4 b = ((const float4*)ea)[i * 2 + 1];
    union { ushort r[8]; uint4 v; } u;
    u.r[0] = f2h(a.x); u.r[1] = f2h(a.y); u.r[2] = f2h(a.z); u.r[3] = f2h(a.w);
    u.r[4] = f2h(b.x); u.r[5] = f2h(b.y); u.r[6] = f2h(b.z); u.r[7] = f2h(b.w);
    ((uint4*)tmp)[i] = u.v;
  }
}

__global__ __launch_bounds__(256) void permute_ea(const ushort* __restrict__ tmp,
                                                  const int* __restrict__ eperm,
                                                  const int* __restrict__ src,
                                                  ushort* __restrict__ ea16,
                                                  int* __restrict__ src_perm, int nE) {
  int t = blockIdx.x * 256 + threadIdx.x;
  int j = t >> 2, part = t & 3;
  if (j < nE) {
    int e = eperm[j];
    ((uint4*)&ea16[(size_t)j * 32])[part] =
        ((const uint4*)&tmp[(size_t)e * 32])[part];
    if (part == 0) src_perm[j] = src[e];
  }
}

__global__ __launch_bounds__(256) void prep_edges_h(const float* __restrict__ ea,
                                                    const int* __restrict__ eperm,
                                                    const int* __restrict__ src,
                                                    ushort* __restrict__ ea16,
                                                    int* __restrict__ src_perm, int nE) {
  int t = blockIdx.x * 256 + threadIdx.x;
  int j = t >> 3, ch = (t & 7) << 2;
  if (j < nE) {
    int e = eperm[j];
    float4 v = *(const float4*)&ea[(size_t)e * 32 + ch];
    ushort4 h;
    h.x = f2h(v.x); h.y = f2h(v.y); h.z = f2h(v.z); h.w = f2h(v.w);
    *(ushort4*)&ea16[(size_t)j * 32 + ch] = h;
    if (ch == 0) src_perm[j] = src[e];
  }
}

// ---------------- weight prep ----------------

__global__ __launch_bounds__(256) void convert_x(const float* __restrict__ x,
                                                 ushort* __restrict__ xb, int n8) {
  int i = blockIdx.x * 256 + threadIdx.x;
  if (i < n8) {
    float4 a = ((const float4*)x)[i * 2];
    float4 b = ((const float4*)x)[i * 2 + 1];
    union { ushort r[8]; uint4 v; } u;
    u.r[0] = f2bf(a.x); u.r[1] = f2bf(a.y); u.r[2] = f2bf(a.z); u.r[3] = f2bf(a.w);
    u.r[4] = f2bf(b.x); u.r[5] = f2bf(b.y); u.r[6] = f2bf(b.z); u.r[7] = f2bf(b.w);
    ((uint4*)xb)[i] = u.v;
  }
}

__global__ __launch_bounds__(256) void prep_w(const float* __restrict__ Wl,
                                              const float* __restrict__ Wr,
                                              ushort* __restrict__ wt1,
                                              ushort* __restrict__ wt2) {
  int idx = blockIdx.x * 256 + threadIdx.x;
  int mat = idx >> 14, rem = idx & 16383;
  int n = rem >> 7, k = rem & 127;
  const float* W = mat ? Wr : Wl;
  ushort* wt = mat ? wt2 : wt1;
  wt[n * 128 + k] = f2bf(W[(size_t)k * 128 + n]);
}

// weh[n][k] = fp16(We[k][n]), n<128, k<32
__global__ __launch_bounds__(256) void prep_we(const float* __restrict__ We,
                                               ushort* __restrict__ weh) {
  int idx = blockIdx.x * 256 + threadIdx.x;
  if (idx < 4096) {
    int n = idx >> 5, k = idx & 31;
    weh[n * 32 + k] = f2h(We[(size_t)k * 128 + n]);
  }
}

// ---------------- MFMA dual GEMM ----------------
#define XPAD 136

__device__ inline bf16x8 load_frag(const ushort* p) {
  union { bf16x8 v; unsigned long long q[2]; } u;
  u.q[0] = *(const unsigned long long*)p;
  u.q[1] = *(const unsigned long long*)(p + 16);
  return u.v;
}

__global__ __launch_bounds__(512) void gemm_mfma_dual(
    const ushort* __restrict__ xb, const ushort* __restrict__ wt1,
    const ushort* __restrict__ wt2, const float* __restrict__ b1,
    const float* __restrict__ b2, ushort* __restrict__ xlh,
    float* __restrict__ y2, int nrows) {
  __shared__ ushort Xs[128 * XPAD];
  __shared__ ushort Ws[128 * XPAD];
  const int tid = threadIdx.x;
  const int r0 = blockIdx.x * 128;

#pragma unroll
  for (int i = 0; i < 4; ++i) {
    int c = tid + i * 512;
    int row = c >> 4, kc = (c & 15) << 3;
    int gr = min(r0 + row, nrows - 1);
    *(uint4*)&Xs[row * XPAD + kc] = *(const uint4*)&xb[(size_t)gr * 128 + kc];
    *(uint4*)&Ws[row * XPAD + kc] = *(const uint4*)&wt1[row * 128 + kc];
  }
  __syncthreads();

  const int wid = tid >> 6, lane = tid & 63;
  const int lr = lane & 15, lg = lane >> 4;
  const int RB = (wid & 3) * 32, CB = (wid >> 2) * 64;

  f32x4 acc1[2][4] = {{{0.f}}};
  f32x4 acc2[2][4] = {{{0.f}}};

#pragma unroll
  for (int ks = 0; ks < 4; ++ks) {
    const int kb = ks * 32 + lg * 4;
    bf16x8 a0 = load_frag(&Xs[(RB + lr) * XPAD + kb]);
    bf16x8 a1 = load_frag(&Xs[(RB + 16 + lr) * XPAD + kb]);
#pragma unroll
    for (int nt = 0; nt < 4; ++nt) {
      const int n = CB + nt * 16 + lr;
      bf16x8 bw = load_frag(&Ws[n * XPAD + kb]);
      acc1[0][nt] = __builtin_amdgcn_mfma_f32_16x16x32_bf16(a0, bw, acc1[0][nt], 0, 0, 0);
      acc1[1][nt] = __builtin_amdgcn_mfma_f32_16x16x32_bf16(a1, bw, acc1[1][nt], 0, 0, 0);
    }
  }
  __syncthreads();
#pragma unroll
  for (int i = 0; i < 4; ++i) {
    int c = tid + i * 512;
    int row = c >> 4, kc = (c & 15) << 3;
    *(uint4*)&Ws[row * XPAD + kc] = *(const uint4*)&wt2[row * 128 + kc];
  }
  __syncthreads();
#pragma unroll
  for (int ks = 0; ks < 4; ++ks) {
    const int kb = ks * 32 + lg * 4;
    bf16x8 a0 = load_frag(&Xs[(RB + lr) * XPAD + kb]);
    bf16x8 a1 = load_frag(&Xs[(RB + 16 + lr) * XPAD + kb]);
#pragma unroll
    for (int nt = 0; nt < 4; ++nt) {
      const int n = CB + nt * 16 + lr;
      bf16x8 bw = load_frag(&Ws[n * XPAD + kb]);
      acc2[0][nt] = __builtin_amdgcn_mfma_f32_16x16x32_bf16(a0, bw, acc2[0][nt], 0, 0, 0);
      acc2[1][nt] = __builtin_amdgcn_mfma_f32_16x16x32_bf16(a1, bw, acc2[1][nt], 0, 0, 0);
    }
  }

#pragma unroll
  for (int nt = 0; nt < 4; ++nt) {
    const int col = CB + nt * 16 + lr;
    const float bb1 = b1[col], bb2 = b2[col];
    const int hoff = ((col & 63) << 1) | (col >> 6);
#pragma unroll
    for (int mt = 0; mt < 2; ++mt) {
#pragma unroll
      for (int r = 0; r < 4; ++r) {
        int gr = r0 + RB + mt * 16 + lg * 4 + r;
        if (gr < nrows) {
          xlh[(size_t)gr * 128 + hoff] = f2h(acc1[mt][nt][r] + bb1);
          y2[(size_t)gr * 128 + col] = acc2[mt][nt][r] + bb2;
        }
      }
    }
  }
}

// ---------------- fused GATv2 layer (MFMA edge projection) ----------------
// Grid-stride over nodes: each wave loads We^T frags (bq) + att once, then
// processes nodes bn, bn+stride, ... Per 16-edge tile: 8 MFMAs compute
// eproj = ea@We; lane holds rows 4*lg..+3 (reg r), col 16*nt+lr. Scores:
// m = D + xr + xl; lrelu; att-dot; packed-f16 butterfly per 16-lane group;
// cross-group combine; softmax-normalize; LN; store.
template <int H, bool OB>
__global__ __launch_bounds__(256) void fused_gat(
    const ushort* __restrict__ xlh, const float* __restrict__ xr,
    const ushort* __restrict__ ea16, const ushort* __restrict__ weh,
    const float* __restrict__ att, const int* __restrict__ rowptr,
    const int* __restrict__ src_perm, const int* __restrict__ nodeorder,
    const float* __restrict__ bias, const float* __restrict__ gam,
    const float* __restrict__ bet, float* __restrict__ out,
    ushort* __restrict__ outb, int nN) {
  const int l = threadIdx.x & 63;
  const int wid = threadIdx.x >> 6;
  const int lr = l & 15, lg = l >> 4;
  const int gwave = blockIdx.x * 4 + wid;
  const int stride = gridDim.x * 4;
  const uint* __restrict__ xlw = (const uint*)xlh;

  // wave-invariant setup: We^T fragments (col n = nt*16+lr,
  // k = 4*lg + (j&3) + 16*(j>>2)) and att
  unsigned long long bq[16];
#pragma unroll
  for (int nt = 0; nt < 8; ++nt) {
    const ushort* p = weh + (size_t)(nt * 16 + lr) * 32 + 4 * lg;
    bq[2 * nt] = *(const unsigned long long*)p;
    bq[2 * nt + 1] = *(const unsigned long long*)(p + 16);
  }
  float attv[8];
#pragma unroll
  for (int nt = 0; nt < 8; ++nt) {
    attv[nt] = att[lr + 16 * nt] * 1.44269504f;  // fold 1/ln2 -> exp2
  }

  for (int bn = gwave; bn < nN; bn += stride) {
    const int n = __builtin_amdgcn_readfirstlane(nodeorder[bn]);
    const int rb = __builtin_amdgcn_readfirstlane(rowptr[n]);
    const int re = __builtin_amdgcn_readfirstlane(rowptr[n + 1]);

    float xrv[8];
#pragma unroll
    for (int nt = 0; nt < 8; ++nt) xrv[nt] = xr[(size_t)n * 128 + lr + 16 * nt];

    float acc[8] = {0.f, 0.f, 0.f, 0.f, 0.f, 0.f, 0.f, 0.f};
    float d0 = 0.f, d1 = 0.f, d2 = 0.f, d3 = 0.f;

    for (int t0 = rb; t0 < re; t0 += 16) {
      // A-frag: row t0+lr (clamped), k = 4*lg+(j&3)+16*(j>>2)
      const int arow = min(t0 + lr, re - 1);
      union { unsigned long long q[2]; h8 v; } ua;
      const ushort* ap = ea16 + (size_t)arow * 32 + 4 * lg;
      ua.q[0] = *(const unsigned long long*)ap;
      ua.q[1] = *(const unsigned long long*)(ap + 16);

      // srcs + xl gathers for my group's rows (t0 + 4*lg + r)
      int sr_[4];
#pragma unroll
      for (int r = 0; r < 4; ++r)
        sr_[r] = src_perm[min(t0 + 4 * lg + r, re - 1)];
      uint u[4][4];
#pragma unroll
      for (int r = 0; r < 4; ++r) {
        const uint* xp = xlw + (size_t)sr_[r] * 64;
#pragma unroll
        for (int q = 0; q < 4; ++q) u[r][q] = xp[lr + 16 * q];
      }

      // eproj: 8 MFMAs
      f32x4 D[8];
#pragma unroll
      for (int nt = 0; nt < 8; ++nt) {
        union { unsigned long long q[2]; h8 v; } ub;
        ub.q[0] = bq[2 * nt];
        ub.q[1] = bq[2 * nt + 1];
        f32x4 z = {0.f, 0.f, 0.f, 0.f};
        D[nt] = __builtin_amdgcn_mfma_f32_16x16x32_f16(ua.v, ub.v, z, 0, 0, 0);
      }

      if (H == 4) {
#pragma unroll
        for (int r = 0; r < 4; ++r) {
          float xv[8];
#pragma unroll
          for (int q = 0; q < 4; ++q) {
            float2 f = __half22float2(*(__half2*)&u[r][q]);
            xv[q] = f.x;
            xv[q + 4] = f.y;
          }
          float p0 = 0.f, p1 = 0.f, p2 = 0.f, p3 = 0.f;
#pragma unroll
          for (int nt = 0; nt < 8; ++nt) {
            float m = D[nt][r] + xrv[nt] + xv[nt];
            m = fmaxf(m, 0.2f * m);
            float pm = m * attv[nt];
            if (nt < 2) p0 += pm;
            else if (nt < 4) p1 += pm;
            else if (nt < 6) p2 += pm;
            else p3 += pm;
          }
          uint pa = pk2(p0, p1), pb = pk2(p2, p3);
#pragma unroll
          for (int o = 1; o <= 8; o <<= 1) {
            pa = swz_add(pa, o);
            pb = swz_add(pb, o);
          }
          float2 sA = __half22float2(*(__half2*)&pa);
          float2 sB = __half22float2(*(__half2*)&pb);
          float w0 = exp2f(fminf(sA.x, 115.f));
          float w1 = exp2f(fminf(sA.y, 115.f));
          float w2 = exp2f(fminf(sB.x, 115.f));
          float w3 = exp2f(fminf(sB.y, 115.f));
          if (t0 + 4 * lg + r >= re) { w0 = 0.f; w1 = 0.f; w2 = 0.f; w3 = 0.f; }
          d0 += w0; d1 += w1; d2 += w2; d3 += w3;
#pragma unroll
          for (int nt = 0; nt < 8; ++nt) {
            float wn = (nt < 2) ? w0 : (nt < 4) ? w1 : (nt < 6) ? w2 : w3;
            acc[nt] += wn * xv[nt];
          }
        }
      } else {
#pragma unroll
        for (int rp = 0; rp < 2; ++rp) {
          const int ra = 2 * rp, rbx = 2 * rp + 1;
          float xva[8], xvb[8];
#pragma unroll
          for (int q = 0; q < 4; ++q) {
            float2 fa = __half22float2(*(__half2*)&u[ra][q]);
            float2 fb = __half22float2(*(__half2*)&u[rbx][q]);
            xva[q] = fa.x; xva[q + 4] = fa.y;
            xvb[q] = fb.x; xvb[q + 4] = fb.y;
          }
          float pA = 0.f, pB = 0.f;
#pragma unroll
          for (int nt = 0; nt < 8; ++nt) {
            float ma = D[nt][ra] + xrv[nt] + xva[nt];
            float mb = D[nt][rbx] + xrv[nt] + xvb[nt];
            ma = fmaxf(ma, 0.2f * ma);
            mb = fmaxf(mb, 0.2f * mb);
            pA += ma * attv[nt];
            pB += mb * attv[nt];
          }
          uint pa = pk2(pA, pB);
#pragma unroll
          for (int o = 1; o <= 8; o <<= 1) pa = swz_add(pa, o);
          float2 s = __half22float2(*(__half2*)&pa);
          float w0 = exp2f(fminf(s.x, 115.f));
          float w1 = exp2f(fminf(s.y, 115.f));
          if (t0 + 4 * lg + ra >= re) w0 = 0.f;
          if (t0 + 4 * lg + rbx >= re) w1 = 0.f;
          d0 += w0 + w1;
#pragma unroll
          for (int nt = 0; nt < 8; ++nt) acc[nt] += w0 * xva[nt] + w1 * xvb[nt];
        }
      }
    }

    // cross-group combine (groups processed distinct edge rows)
#pragma unroll
    for (int o = 16; o <= 32; o <<= 1) {
#pragma unroll
      for (int nt = 0; nt < 8; ++nt) acc[nt] += __shfl_xor(acc[nt], o);
      d0 += __shfl_xor(d0, o);
      if (H == 4) {
        d1 += __shfl_xor(d1, o);
        d2 += __shfl_xor(d2, o);
        d3 += __shfl_xor(d3, o);
      }
    }

    const float rd0 = (d0 > 0.f) ? 1.f / d0 : 0.f;
    const float rd1 = (H == 4) ? ((d1 > 0.f) ? 1.f / d1 : 0.f) : rd0;
    const float rd2 = (H == 4) ? ((d2 > 0.f) ? 1.f / d2 : 0.f) : rd0;
    const float rd3 = (H == 4) ? ((d3 > 0.f) ? 1.f / d3 : 0.f) : rd0;

    float y[8];
    float s1 = 0.f, s2 = 0.f;
#pragma unroll
    for (int nt = 0; nt < 8; ++nt) {
      const int c = lr + 16 * nt;
      const float rdn =
          (H == 1) ? rd0 : ((nt < 2) ? rd0 : (nt < 4) ? rd1 : (nt < 6) ? rd2 : rd3);
      y[nt] = acc[nt] * rdn + bias[c];
      s1 += y[nt];
      s2 += y[nt] * y[nt];
    }
#pragma unroll
    for (int o = 1; o <= 8; o <<= 1) {  // 16-lane group holds all 128 cols
      s1 += __shfl_xor(s1, o);
      s2 += __shfl_xor(s2, o);
    }
    const float mu = s1 * (1.f / 128.f);
    const float var = s2 * (1.f / 128.f) - mu * mu;
    const float rstd = rsqrtf(var + 1e-5f);
    if (lg == 0) {  // groups hold identical data; one stores
#pragma unroll
      for (int nt = 0; nt < 8; ++nt) {
        const int c = lr + 16 * nt;
        const float o0 = fmaxf((y[nt] - mu) * rstd * gam[c] + bet[c], 0.f);
        if (OB)
          outb[(size_t)n * 128 + c] = f2bf(o0);
        else
          out[(size_t)n * 128 + c] = o0;
      }
    }
  }
}

extern "C" void kernel_launch(void* const* d_in, const int* in_sizes, int n_in,
                              void* d_out, int out_size, void* d_ws, size_t ws_size,
                              hipStream_t stream) {
  const float* x = (const float*)d_in[0];
  const float* ea = (const float*)d_in[1];
  const int* src = (const int*)d_in[2];
  const int* dst = (const int*)d_in[3];
  const int N = in_sizes[0] / 128;
  const int E = in_sizes[2];

  char* w = (char*)d_ws;
  auto alloc = [&](size_t bytes) {
    char* p = w;
    w += (bytes + 255) & ~(size_t)255;
    return p;
  };
  ushort* xlh = (ushort*)alloc((size_t)N * 128 * 2);
  float* xr = (float*)alloc((size_t)N * 128 * 4);
  ushort* xb = (ushort*)alloc((size_t)N * 128 * 2);
  ushort* wt1 = (ushort*)alloc(128 * 128 * 2);
  ushort* wt2 = (ushort*)alloc(128 * 128 * 2);
  ushort* weh = (ushort*)alloc(128 * 32 * 2);
  int* eperm = (int*)alloc((size_t)E * 4);
  int* rowptr = (int*)alloc((size_t)(N + 1) * 4);
  int* deg = (int*)alloc((size_t)N * 4);
  int* cnt = (int*)alloc((size_t)N * 4);
  int* nodeorder = (int*)alloc((size_t)N * 4);
  int* dh = (int*)alloc(256 * 4);
  int* dbase = (int*)alloc(256 * 4);
  int* dcnt = (int*)alloc(256 * 4);
  int* bsum = (int*)alloc(1024 * 4);
  ushort* ea16 = (ushort*)alloc((size_t)E * 32 * 2);
  int* src_perm = (int*)alloc((size_t)E * 4);
  size_t used = (size_t)(w - (char*)d_ws);
  const bool SPLIT_OK = (used + (size_t)E * 32 * 2 + 256 <= ws_size);
  ushort* tmp16 = nullptr;
  if (SPLIT_OK) tmp16 = (ushort*)alloc((size_t)E * 32 * 2);

  hipMemsetAsync(deg, 0, (size_t)N * 4, stream);
  hipMemsetAsync(cnt, 0, (size_t)N * 4, stream);
  hipMemsetAsync(dh, 0, 256 * 4, stream);
  hipMemsetAsync(dcnt, 0, 256 * 4, stream);
  hist_kernel<<<(E + 255) / 256, 256, 0, stream>>>(dst, deg, E);
  int nb = (N + 1023) / 1024;
  scan_blocks<<<nb, 1024, 0, stream>>>(deg, rowptr, bsum, N);
  scan_carry<<<1, 64, 0, stream>>>(bsum, nb);
  scan_apply<<<nb, 1024, 0, stream>>>(rowptr, bsum, N);
  scatter_kernel<<<(E + 255) / 256, 256, 0, stream>>>(dst, rowptr, cnt, eperm, E);
  deg_hist<<<(N + 255) / 256, 256, 0, stream>>>(rowptr, dh, N);
  deg_scan<<<1, 256, 0, stream>>>(dh, dbase);
  deg_scatter<<<(N + 255) / 256, 256, 0, stream>>>(rowptr, dbase, dcnt, nodeorder, N);

  if (SPLIT_OK) {
    convert_ea<<<(E * 4 + 255) / 256, 256, 0, stream>>>(ea, tmp16, E * 4);
    permute_ea<<<((size_t)E * 4 + 255) / 256, 256, 0, stream>>>(tmp16, eperm, src,
                                                                ea16, src_perm, E);
  } else {
    prep_edges_h<<<((size_t)E * 8 + 255) / 256, 256, 0, stream>>>(ea, eperm, src,
                                                                  ea16, src_perm, E);
  }

  int n8 = N * 128 / 8;
  convert_x<<<(n8 + 255) / 256, 256, 0, stream>>>(x, xb, n8);

  for (int l = 0; l < 3; ++l) {
    int bi = 4 + 9 * l;
    const float* Wl = (const float*)d_in[bi + 0];
    const float* bl = (const float*)d_in[bi + 1];
    const float* Wr = (const float*)d_in[bi + 2];
    const float* br = (const float*)d_in[bi + 3];
    const float* We = (const float*)d_in[bi + 4];
    const float* att = (const float*)d_in[bi + 5];
    const float* bo = (const float*)d_in[bi + 6];
    const float* gg = (const float*)d_in[bi + 7];
    const float* be = (const float*)d_in[bi + 8];

    prep_w<<<128, 256, 0, stream>>>(Wl, Wr, wt1, wt2);
    prep_we<<<16, 256, 0, stream>>>(We, weh);
    gemm_mfma_dual<<<(N + 127) / 128, 512, 0, stream>>>(xb, wt1, wt2, bl, br, xlh, xr, N);
    const int fGrid = 1024;  // 4096 waves, grid-stride over nodes
    if (l < 2) {
      fused_gat<4, true><<<fGrid, 256, 0, stream>>>(xlh, xr, ea16, weh, att, rowptr,
                                                    src_perm, nodeorder, bo, gg, be,
                                                    nullptr, xb, N);
    } else {
      fused_gat<1, false><<<fGrid, 256, 0, stream>>>(xlh, xr, ea16, weh, att, rowptr,
                                                     src_perm, nodeorder, bo, gg, be,
                                                     (float*)d_out, nullptr, N);
    }
  }
}

// Round 16
// 837.088 us; speedup vs baseline: 1.0509x; 1.0509x over previous
//
#include <hip/hip_runtime.h>
#include <hip/hip_fp16.h>

// ---------------------------------------------------------------------------
// GATv2 3-layer GNN encoder. N=50000 nodes, E=800000 edges, dims 128.
// CSR build + degree-sort + fp16 edge-stream permute (once) + merged weight
// prep (all layers); per layer: [MFMA dual GEMM (wave-per-16-rows, packed
// xlh stores), fused layer (r13 config: 1 wave/node, MFMA edge projection)].
// ---------------------------------------------------------------------------

typedef __attribute__((ext_vector_type(8))) short bf16x8;
typedef __attribute__((ext_vector_type(4))) float f32x4;
typedef __fp16 h2 __attribute__((ext_vector_type(2)));
typedef __fp16 h8 __attribute__((ext_vector_type(8)));

__device__ inline ushort f2bf(float f) {
  unsigned u = __float_as_uint(f);
  u += 0x7FFF + ((u >> 16) & 1);
  return (ushort)(u >> 16);
}

__device__ inline ushort f2h(float f) {
  __half h = __float2half(f);
  return *(ushort*)&h;
}

__device__ inline uint pk2(float a, float b) {
#if __has_builtin(__builtin_amdgcn_cvt_pkrtz)
  h2 r = __builtin_amdgcn_cvt_pkrtz(a, b);
  return *(uint*)&r;
#else
  return (uint)f2h(a) | ((uint)f2h(b) << 16);
#endif
}

__device__ inline uint swz_add(uint p, int o) {  // packed-f16 butterfly step
  int q = __shfl_xor(*(int*)&p, o);
  __half2 r = __hadd2(*(__half2*)&p, *(__half2*)&q);
  return *(uint*)&r;
}

// ---------------- CSR build ----------------

__global__ __launch_bounds__(256) void hist_kernel(const int* __restrict__ dst,
                                                   int* __restrict__ deg, int nE) {
  int i = blockIdx.x * 256 + threadIdx.x;
  if (i < nE) atomicAdd(&deg[dst[i]], 1);
}

__global__ __launch_bounds__(1024) void scan_blocks(const int* __restrict__ deg,
                                                    int* __restrict__ rowptr,
                                                    int* __restrict__ bsum, int n) {
  __shared__ int wsum[16];
  __shared__ int wbase[16];
  int tid = threadIdx.x, wid = tid >> 6, lane = tid & 63;
  int i = blockIdx.x * 1024 + tid;
  int v = (i < n) ? deg[i] : 0;
#pragma unroll
  for (int o = 1; o < 64; o <<= 1) {
    int t = __shfl_up(v, o);
    if (lane >= o) v += t;
  }
  if (lane == 63) wsum[wid] = v;
  __syncthreads();
  if (tid < 16) {
    int s = wsum[tid];
#pragma unroll
    for (int o = 1; o < 16; o <<= 1) {
      int t = __shfl_up(s, o);
      if (tid >= o) s += t;
    }
    wbase[tid] = s;
  }
  __syncthreads();
  int base = (wid > 0) ? wbase[wid - 1] : 0;
  if (i < n) rowptr[i + 1] = base + v;
  if (tid == 1023) bsum[blockIdx.x] = wbase[15];
}

__global__ __launch_bounds__(64) void scan_carry(int* __restrict__ bsum, int nb) {
  int lane = threadIdx.x;
  int carry = 0;
  for (int base = 0; base < nb; base += 64) {
    int i = base + lane;
    int v = (i < nb) ? bsum[i] : 0;
    int inc = v;
#pragma unroll
    for (int o = 1; o < 64; o <<= 1) {
      int t = __shfl_up(inc, o);
      if (lane >= o) inc += t;
    }
    if (i < nb) bsum[i] = carry + inc - v;
    carry += __shfl(inc, 63);
  }
}

__global__ __launch_bounds__(1024) void scan_apply(int* __restrict__ rowptr,
                                                   const int* __restrict__ bsum, int n) {
  int i = blockIdx.x * 1024 + threadIdx.x;
  if (i < n) rowptr[i + 1] += bsum[blockIdx.x];
  if (i == 0) rowptr[0] = 0;
}

__global__ __launch_bounds__(256) void scatter_kernel(const int* __restrict__ dst,
                                                      const int* __restrict__ rowptr,
                                                      int* __restrict__ cnt,
                                                      int* __restrict__ eperm, int nE) {
  int i = blockIdx.x * 256 + threadIdx.x;
  if (i < nE) {
    int d = dst[i];
    int p = atomicAdd(&cnt[d], 1);
    eperm[rowptr[d] + p] = i;
  }
}

__global__ __launch_bounds__(256) void deg_hist(const int* __restrict__ rowptr,
                                                int* __restrict__ dh, int nN) {
  int i = blockIdx.x * 256 + threadIdx.x;
  if (i < nN) {
    int dg = min(rowptr[i + 1] - rowptr[i], 255);
    atomicAdd(&dh[dg], 1);
  }
}

__global__ __launch_bounds__(256) void deg_scan(const int* __restrict__ dh,
                                                int* __restrict__ dbase) {
  __shared__ int s[256];
  int t = threadIdx.x;
  s[t] = dh[t];
  __syncthreads();
  for (int ofs = 1; ofs < 256; ofs <<= 1) {
    int v = (t >= ofs) ? s[t - ofs] : 0;
    __syncthreads();
    s[t] += v;
    __syncthreads();
  }
  dbase[t] = s[255] - s[t];
}

__global__ __launch_bounds__(256) void deg_scatter(const int* __restrict__ rowptr,
                                                   const int* __restrict__ dbase,
                                                   int* __restrict__ dcnt,
                                                   int* __restrict__ nodeorder, int nN) {
  int i = blockIdx.x * 256 + threadIdx.x;
  if (i < nN) {
    int dg = min(rowptr[i + 1] - rowptr[i], 255);
    int p = atomicAdd(&dcnt[dg], 1);
    nodeorder[dbase[dg] + p] = i;
  }
}

// ---------------- edge stream prep ----------------

__global__ __launch_bounds__(256) void convert_ea(const float* __restrict__ ea,
                                                  ushort* __restrict__ tmp, int n8) {
  int i = blockIdx.x * 256 + threadIdx.x;
  if (i < n8) {
    float4 a = ((const float4*)ea)[i * 2];
    float4 b = ((const float4*)ea)[i * 2 + 1];
    union { ushort r[8]; uint4 v; } u;
    u.r[0] = f2h(a.x); u.r[1] = f2h(a.y); u.r[2] = f2h(a.z); u.r[3] = f2h(a.w);
    u.r[4] = f2h(b.x); u.r[5] = f2h(b.y); u.r[6] = f2h(b.z); u.r[7] = f2h(b.w);
    ((uint4*)tmp)[i] = u.v;
  }
}

// one thread per edge row (64B): random read, coalesced write
__global__ __launch_bounds__(256) void permute_ea(const ushort* __restrict__ tmp,
                                                  const int* __restrict__ eperm,
                                                  const int* __restrict__ src,
                                                  ushort* __restrict__ ea16,
                                                  int* __restrict__ src_perm, int nE) {
  int j = blockIdx.x * 256 + threadIdx.x;
  if (j < nE) {
    int e = eperm[j];
    const uint4* s = (const uint4*)&tmp[(size_t)e * 32];
    uint4 a = s[0], b = s[1], c = s[2], d = s[3];
    uint4* o = (uint4*)&ea16[(size_t)j * 32];
    o[0] = a; o[1] = b; o[2] = c; o[3] = d;
    src_perm[j] = src[e];
  }
}

__global__ __launch_bounds__(256) void prep_edges_h(const float* __restrict__ ea,
                                                    const int* __restrict__ eperm,
                                                    const int* __restrict__ src,
                                                    ushort* __restrict__ ea16,
                                                    int* __restrict__ src_perm, int nE) {
  int t = blockIdx.x * 256 + threadIdx.x;
  int j = t >> 3, ch = (t & 7) << 2;
  if (j < nE) {
    int e = eperm[j];
    float4 v = *(const float4*)&ea[(size_t)e * 32 + ch];
    ushort4 h;
    h.x = f2h(v.x); h.y = f2h(v.y); h.z = f2h(v.z); h.w = f2h(v.w);
    *(ushort4*)&ea16[(size_t)j * 32 + ch] = h;
    if (ch == 0) src_perm[j] = src[e];
  }
}

// ---------------- weight prep (all layers, one kernel) ----------------

__global__ __launch_bounds__(256) void convert_x(const float* __restrict__ x,
                                                 ushort* __restrict__ xb, int n8) {
  int i = blockIdx.x * 256 + threadIdx.x;
  if (i < n8) {
    float4 a = ((const float4*)x)[i * 2];
    float4 b = ((const float4*)x)[i * 2 + 1];
    union { ushort r[8]; uint4 v; } u;
    u.r[0] = f2bf(a.x); u.r[1] = f2bf(a.y); u.r[2] = f2bf(a.z); u.r[3] = f2bf(a.w);
    u.r[4] = f2bf(b.x); u.r[5] = f2bf(b.y); u.r[6] = f2bf(b.z); u.r[7] = f2bf(b.w);
    ((uint4*)xb)[i] = u.v;
  }
}

// per layer: wt1/wt2 = bf16(W^T) [16384 each], weh = fp16(We^T) [4096]
__global__ __launch_bounds__(256) void prep_weights(
    const float* __restrict__ Wl0, const float* __restrict__ Wr0,
    const float* __restrict__ We0, const float* __restrict__ Wl1,
    const float* __restrict__ Wr1, const float* __restrict__ We1,
    const float* __restrict__ Wl2, const float* __restrict__ Wr2,
    const float* __restrict__ We2, ushort* __restrict__ wt1,
    ushort* __restrict__ wt2, ushort* __restrict__ weh) {
  int idx = blockIdx.x * 256 + threadIdx.x;
  int l = idx / 36864, rem = idx % 36864;
  if (l >= 3) return;
  const float* Wl = (l == 0) ? Wl0 : (l == 1) ? Wl1 : Wl2;
  const float* Wr = (l == 0) ? Wr0 : (l == 1) ? Wr1 : Wr2;
  const float* We = (l == 0) ? We0 : (l == 1) ? We1 : We2;
  if (rem < 16384) {
    int n = rem >> 7, k = rem & 127;
    wt1[l * 16384 + n * 128 + k] = f2bf(Wl[(size_t)k * 128 + n]);
  } else if (rem < 32768) {
    int r2 = rem - 16384;
    int n = r2 >> 7, k = r2 & 127;
    wt2[l * 16384 + n * 128 + k] = f2bf(Wr[(size_t)k * 128 + n]);
  } else {
    int r2 = rem - 32768;
    int n = r2 >> 5, k = r2 & 31;
    weh[l * 4096 + n * 32 + k] = f2h(We[(size_t)k * 128 + n]);
  }
}

// ---------------- MFMA dual GEMM ----------------
// 8 waves/block; wave owns 16 rows x ALL 128 cols. A-frags direct from
// global (X read once); W staged in ONE 34.8KB LDS buffer per matrix.
// xlh written as packed uint (fp16 pair c,c+64) -- full-density coalesced.
#define XPAD 136

__device__ inline bf16x8 load_frag_g(const ushort* p, int stride_elems) {
  union { bf16x8 v; unsigned long long q[2]; } u;
  u.q[0] = *(const unsigned long long*)p;
  u.q[1] = *(const unsigned long long*)(p + 16);
  (void)stride_elems;
  return u.v;
}

__global__ __launch_bounds__(512) void gemm_mfma_dual(
    const ushort* __restrict__ xb, const ushort* __restrict__ wt1,
    const ushort* __restrict__ wt2, const float* __restrict__ b1,
    const float* __restrict__ b2, ushort* __restrict__ xlh,
    float* __restrict__ y2, int nrows) {
  __shared__ ushort Ws[128 * XPAD];
  const int tid = threadIdx.x;
  const int wid = tid >> 6, lane = tid & 63;
  const int lr = lane & 15, lg = lane >> 4;
  const int r0 = blockIdx.x * 128;
  const int rw = r0 + wid * 16;  // wave's 16-row block
  uint* __restrict__ xlw = (uint*)xlh;

  // A-frags: wave's 16 rows, 4 k-slices (read once, reused both matrices)
  bf16x8 afr[4];
  const int arow = min(rw + lr, nrows - 1);
#pragma unroll
  for (int ks = 0; ks < 4; ++ks) {
    afr[ks] = load_frag_g(&xb[(size_t)arow * 128 + ks * 32 + lg * 4], 0);
  }

#pragma unroll
  for (int m = 0; m < 2; ++m) {
    const ushort* wt = m ? wt2 : wt1;
    // stage W^T into LDS (16384 elems = 2048 uint4, 512 thr -> 4 iters)
    __syncthreads();  // (m==1: waves done reading previous W)
#pragma unroll
    for (int i = 0; i < 4; ++i) {
      int c = tid + i * 512;
      int row = c >> 4, kc = (c & 15) << 3;
      *(uint4*)&Ws[row * XPAD + kc] = *(const uint4*)&wt[row * 128 + kc];
    }
    __syncthreads();

    f32x4 acc[8];
#pragma unroll
    for (int nt = 0; nt < 8; ++nt) acc[nt] = f32x4{0.f, 0.f, 0.f, 0.f};

#pragma unroll
    for (int ks = 0; ks < 4; ++ks) {
      const int kb = ks * 32 + lg * 4;
#pragma unroll
      for (int nt = 0; nt < 8; ++nt) {
        bf16x8 bw = load_frag_g(&Ws[(nt * 16 + lr) * XPAD + kb], 0);
        acc[nt] = __builtin_amdgcn_mfma_f32_16x16x32_bf16(afr[ks], bw, acc[nt], 0, 0, 0);
      }
    }

    if (m == 0) {
      // xlh packed: pair (c, c+64) = (nt*16+lr, (nt+4)*16+lr)
#pragma unroll
      for (int nt = 0; nt < 4; ++nt) {
        const float bbL = b1[nt * 16 + lr];
        const float bbH = b1[(nt + 4) * 16 + lr];
#pragma unroll
        for (int r = 0; r < 4; ++r) {
          int gr = rw + lg * 4 + r;
          if (gr < nrows) {
            xlw[(size_t)gr * 64 + nt * 16 + lr] =
                pk2(acc[nt][r] + bbL, acc[nt + 4][r] + bbH);
          }
        }
      }
    } else {
#pragma unroll
      for (int nt = 0; nt < 8; ++nt) {
        const float bb = b2[nt * 16 + lr];
#pragma unroll
        for (int r = 0; r < 4; ++r) {
          int gr = rw + lg * 4 + r;
          if (gr < nrows) y2[(size_t)gr * 128 + nt * 16 + lr] = acc[nt][r] + bb;
        }
      }
    }
  }
}

// ---------------- fused GATv2 layer (MFMA edge projection, r13 config) -----
// ONE wave per 64-thread block. Per 16-edge tile: A = ea16 rows (fp16),
// D[nt] = mfma_f32_16x16x32_f16(A, We^T[nt]); lane holds rows 4*lg..+3
// (reg r), col 16*nt+lr. Scores: m = D + xr + xl; lrelu; att-dot; packed-f16
// butterfly per 16-lane group; cross-group combine; softmax; LN; store.
template <int H, bool OB>
__global__ __launch_bounds__(64) void fused_gat(
    const ushort* __restrict__ xlh, const float* __restrict__ xr,
    const ushort* __restrict__ ea16, const ushort* __restrict__ weh,
    const float* __restrict__ att, const int* __restrict__ rowptr,
    const int* __restrict__ src_perm, const int* __restrict__ nodeorder,
    const float* __restrict__ bias, const float* __restrict__ gam,
    const float* __restrict__ bet, float* __restrict__ out,
    ushort* __restrict__ outb, int nN) {
  const int l = threadIdx.x;
  const int lr = l & 15, lg = l >> 4;
  const int n = __builtin_amdgcn_readfirstlane(nodeorder[blockIdx.x]);
  const int rb = __builtin_amdgcn_readfirstlane(rowptr[n]);
  const int re = __builtin_amdgcn_readfirstlane(rowptr[n + 1]);
  const uint* __restrict__ xlw = (const uint*)xlh;

  unsigned long long bq[16];
#pragma unroll
  for (int nt = 0; nt < 8; ++nt) {
    const ushort* p = weh + (size_t)(nt * 16 + lr) * 32 + 4 * lg;
    bq[2 * nt] = *(const unsigned long long*)p;
    bq[2 * nt + 1] = *(const unsigned long long*)(p + 16);
  }

  float attv[8], xrv[8];
#pragma unroll
  for (int nt = 0; nt < 8; ++nt) {
    attv[nt] = att[lr + 16 * nt] * 1.44269504f;
    xrv[nt] = xr[(size_t)n * 128 + lr + 16 * nt];
  }

  float acc[8] = {0.f, 0.f, 0.f, 0.f, 0.f, 0.f, 0.f, 0.f};
  float d0 = 0.f, d1 = 0.f, d2 = 0.f, d3 = 0.f;

  for (int t0 = rb; t0 < re; t0 += 16) {
    const int arow = min(t0 + lr, re - 1);
    union { unsigned long long q[2]; h8 v; } ua;
    const ushort* ap = ea16 + (size_t)arow * 32 + 4 * lg;
    ua.q[0] = *(const unsigned long long*)ap;
    ua.q[1] = *(const unsigned long long*)(ap + 16);

    int sr_[4];
#pragma unroll
    for (int r = 0; r < 4; ++r)
      sr_[r] = src_perm[min(t0 + 4 * lg + r, re - 1)];
    uint u[4][4];
#pragma unroll
    for (int r = 0; r < 4; ++r) {
      const uint* xp = xlw + (size_t)sr_[r] * 64;
#pragma unroll
      for (int q = 0; q < 4; ++q) u[r][q] = xp[lr + 16 * q];
    }

    f32x4 D[8];
#pragma unroll
    for (int nt = 0; nt < 8; ++nt) {
      union { unsigned long long q[2]; h8 v; } ub;
      ub.q[0] = bq[2 * nt];
      ub.q[1] = bq[2 * nt + 1];
      f32x4 z = {0.f, 0.f, 0.f, 0.f};
      D[nt] = __builtin_amdgcn_mfma_f32_16x16x32_f16(ua.v, ub.v, z, 0, 0, 0);
    }

    if (H == 4) {
#pragma unroll
      for (int r = 0; r < 4; ++r) {
        float xv[8];
#pragma unroll
        for (int q = 0; q < 4; ++q) {
          float2 f = __half22float2(*(__half2*)&u[r][q]);
          xv[q] = f.x;
          xv[q + 4] = f.y;
        }
        float p0 = 0.f, p1 = 0.f, p2 = 0.f, p3 = 0.f;
#pragma unroll
        for (int nt = 0; nt < 8; ++nt) {
          float m = D[nt][r] + xrv[nt] + xv[nt];
          m = fmaxf(m, 0.2f * m);
          float pm = m * attv[nt];
          if (nt < 2) p0 += pm;
          else if (nt < 4) p1 += pm;
          else if (nt < 6) p2 += pm;
          else p3 += pm;
        }
        uint pa = pk2(p0, p1), pb = pk2(p2, p3);
#pragma unroll
        for (int o = 1; o <= 8; o <<= 1) {
          pa = swz_add(pa, o);
          pb = swz_add(pb, o);
        }
        float2 sA = __half22float2(*(__half2*)&pa);
        float2 sB = __half22float2(*(__half2*)&pb);
        float w0 = exp2f(fminf(sA.x, 115.f));
        float w1 = exp2f(fminf(sA.y, 115.f));
        float w2 = exp2f(fminf(sB.x, 115.f));
        float w3 = exp2f(fminf(sB.y, 115.f));
        if (t0 + 4 * lg + r >= re) { w0 = 0.f; w1 = 0.f; w2 = 0.f; w3 = 0.f; }
        d0 += w0; d1 += w1; d2 += w2; d3 += w3;
#pragma unroll
        for (int nt = 0; nt < 8; ++nt) {
          float wn = (nt < 2) ? w0 : (nt < 4) ? w1 : (nt < 6) ? w2 : w3;
          acc[nt] += wn * xv[nt];
        }
      }
    } else {
#pragma unroll
      for (int rp = 0; rp < 2; ++rp) {
        const int ra = 2 * rp, rbx = 2 * rp + 1;
        float xva[8], xvb[8];
#pragma unroll
        for (int q = 0; q < 4; ++q) {
          float2 fa = __half22float2(*(__half2*)&u[ra][q]);
          float2 fb = __half22float2(*(__half2*)&u[rbx][q]);
          xva[q] = fa.x; xva[q + 4] = fa.y;
          xvb[q] = fb.x; xvb[q + 4] = fb.y;
        }
        float pA = 0.f, pB = 0.f;
#pragma unroll
        for (int nt = 0; nt < 8; ++nt) {
          float ma = D[nt][ra] + xrv[nt] + xva[nt];
          float mb = D[nt][rbx] + xrv[nt] + xvb[nt];
          ma = fmaxf(ma, 0.2f * ma);
          mb = fmaxf(mb, 0.2f * mb);
          pA += ma * attv[nt];
          pB += mb * attv[nt];
        }
        uint pa = pk2(pA, pB);
#pragma unroll
        for (int o = 1; o <= 8; o <<= 1) pa = swz_add(pa, o);
        float2 s = __half22float2(*(__half2*)&pa);
        float w0 = exp2f(fminf(s.x, 115.f));
        float w1 = exp2f(fminf(s.y, 115.f));
        if (t0 + 4 * lg + ra >= re) w0 = 0.f;
        if (t0 + 4 * lg + rbx >= re) w1 = 0.f;
        d0 += w0 + w1;
#pragma unroll
        for (int nt = 0; nt < 8; ++nt) acc[nt] += w0 * xva[nt] + w1 * xvb[nt];
      }
    }
  }

#pragma unroll
  for (int o = 16; o <= 32; o <<= 1) {
#pragma unroll
    for (int nt = 0; nt < 8; ++nt) acc[nt] += __shfl_xor(acc[nt], o);
    d0 += __shfl_xor(d0, o);
    if (H == 4) {
      d1 += __shfl_xor(d1, o);
      d2 += __shfl_xor(d2, o);
      d3 += __shfl_xor(d3, o);
    }
  }

  const float rd0 = (d0 > 0.f) ? 1.f / d0 : 0.f;
  const float rd1 = (H == 4) ? ((d1 > 0.f) ? 1.f / d1 : 0.f) : rd0;
  const float rd2 = (H == 4) ? ((d2 > 0.f) ? 1.f / d2 : 0.f) : rd0;
  const float rd3 = (H == 4) ? ((d3 > 0.f) ? 1.f / d3 : 0.f) : rd0;

  float y[8];
  float s1 = 0.f, s2 = 0.f;
#pragma unroll
  for (int nt = 0; nt < 8; ++nt) {
    const int c = lr + 16 * nt;
    const float rdn =
        (H == 1) ? rd0 : ((nt < 2) ? rd0 : (nt < 4) ? rd1 : (nt < 6) ? rd2 : rd3);
    y[nt] = acc[nt] * rdn + bias[c];
    s1 += y[nt];
    s2 += y[nt] * y[nt];
  }
#pragma unroll
  for (int o = 1; o <= 8; o <<= 1) {
    s1 += __shfl_xor(s1, o);
    s2 += __shfl_xor(s2, o);
  }
  const float mu = s1 * (1.f / 128.f);
  const float var = s2 * (1.f / 128.f) - mu * mu;
  const float rstd = rsqrtf(var + 1e-5f);
  if (lg == 0) {
#pragma unroll
    for (int nt = 0; nt < 8; ++nt) {
      const int c = lr + 16 * nt;
      const float o0 = fmaxf((y[nt] - mu) * rstd * gam[c] + bet[c], 0.f);
      if (OB)
        outb[(size_t)n * 128 + c] = f2bf(o0);
      else
        out[(size_t)n * 128 + c] = o0;
    }
  }
}

extern "C" void kernel_launch(void* const* d_in, const int* in_sizes, int n_in,
                              void* d_out, int out_size, void* d_ws, size_t ws_size,
                              hipStream_t stream) {
  const float* x = (const float*)d_in[0];
  const float* ea = (const float*)d_in[1];
  const int* src = (const int*)d_in[2];
  const int* dst = (const int*)d_in[3];
  const int N = in_sizes[0] / 128;
  const int E = in_sizes[2];

  char* w = (char*)d_ws;
  auto alloc = [&](size_t bytes) {
    char* p = w;
    w += (bytes + 255) & ~(size_t)255;
    return p;
  };
  ushort* xlh = (ushort*)alloc((size_t)N * 128 * 2);
  float* xr = (float*)alloc((size_t)N * 128 * 4);
  ushort* xb = (ushort*)alloc((size_t)N * 128 * 2);
  ushort* wt1 = (ushort*)alloc(3 * 16384 * 2);
  ushort* wt2 = (ushort*)alloc(3 * 16384 * 2);
  ushort* weh = (ushort*)alloc(3 * 4096 * 2);
  int* eperm = (int*)alloc((size_t)E * 4);
  int* rowptr = (int*)alloc((size_t)(N + 1) * 4);
  int* deg = (int*)alloc((size_t)N * 4);
  int* cnt = (int*)alloc((size_t)N * 4);
  int* nodeorder = (int*)alloc((size_t)N * 4);
  int* dh = (int*)alloc(256 * 4);
  int* dbase = (int*)alloc(256 * 4);
  int* dcnt = (int*)alloc(256 * 4);
  int* bsum = (int*)alloc(1024 * 4);
  ushort* ea16 = (ushort*)alloc((size_t)E * 32 * 2);
  int* src_perm = (int*)alloc((size_t)E * 4);
  size_t used = (size_t)(w - (char*)d_ws);
  const bool SPLIT_OK = (used + (size_t)E * 32 * 2 + 256 <= ws_size);
  ushort* tmp16 = nullptr;
  if (SPLIT_OK) tmp16 = (ushort*)alloc((size_t)E * 32 * 2);

  hipMemsetAsync(deg, 0, (size_t)N * 4, stream);
  hipMemsetAsync(cnt, 0, (size_t)N * 4, stream);
  hipMemsetAsync(dh, 0, 256 * 4, stream);
  hipMemsetAsync(dcnt, 0, 256 * 4, stream);
  hist_kernel<<<(E + 255) / 256, 256, 0, stream>>>(dst, deg, E);
  int nb = (N + 1023) / 1024;
  scan_blocks<<<nb, 1024, 0, stream>>>(deg, rowptr, bsum, N);
  scan_carry<<<1, 64, 0, stream>>>(bsum, nb);
  scan_apply<<<nb, 1024, 0, stream>>>(rowptr, bsum, N);
  scatter_kernel<<<(E + 255) / 256, 256, 0, stream>>>(dst, rowptr, cnt, eperm, E);
  deg_hist<<<(N + 255) / 256, 256, 0, stream>>>(rowptr, dh, N);
  deg_scan<<<1, 256, 0, stream>>>(dh, dbase);
  deg_scatter<<<(N + 255) / 256, 256, 0, stream>>>(rowptr, dbase, dcnt, nodeorder, N);

  if (SPLIT_OK) {
    convert_ea<<<(E * 4 + 255) / 256, 256, 0, stream>>>(ea, tmp16, E * 4);
    permute_ea<<<(E + 255) / 256, 256, 0, stream>>>(tmp16, eperm, src, ea16,
                                                    src_perm, E);
  } else {
    prep_edges_h<<<((size_t)E * 8 + 255) / 256, 256, 0, stream>>>(ea, eperm, src,
                                                                  ea16, src_perm, E);
  }

  int n8 = N * 128 / 8;
  convert_x<<<(n8 + 255) / 256, 256, 0, stream>>>(x, xb, n8);

  prep_weights<<<(3 * 36864 + 255) / 256, 256, 0, stream>>>(
      (const float*)d_in[4], (const float*)d_in[6], (const float*)d_in[8],
      (const float*)d_in[13], (const float*)d_in[15], (const float*)d_in[17],
      (const float*)d_in[22], (const float*)d_in[24], (const float*)d_in[26],
      wt1, wt2, weh);

  for (int l = 0; l < 3; ++l) {
    int bi = 4 + 9 * l;
    const float* bl = (const float*)d_in[bi + 1];
    const float* br = (const float*)d_in[bi + 3];
    const float* att = (const float*)d_in[bi + 5];
    const float* bo = (const float*)d_in[bi + 6];
    const float* gg = (const float*)d_in[bi + 7];
    const float* be = (const float*)d_in[bi + 8];

    gemm_mfma_dual<<<(N + 127) / 128, 512, 0, stream>>>(
        xb, wt1 + l * 16384, wt2 + l * 16384, bl, br, xlh, xr, N);
    if (l < 2) {
      fused_gat<4, true><<<N, 64, 0, stream>>>(xlh, xr, ea16, weh + l * 4096, att,
                                               rowptr, src_perm, nodeorder, bo, gg,
                                               be, nullptr, xb, N);
    } else {
      fused_gat<1, false><<<N, 64, 0, stream>>>(xlh, xr, ea16, weh + l * 4096, att,
                                                rowptr, src_perm, nodeorder, bo, gg,
                                                be, (float*)d_out, nullptr, N);
    }
  }
}

// Round 17
// 523.751 us; speedup vs baseline: 1.6796x; 1.5983x over previous
//
#include <hip/hip_runtime.h>
#include <hip/hip_fp16.h>

// ---------------------------------------------------------------------------
// GATv2 3-layer GNN encoder. N=50000 nodes, E=800000 edges, dims 128.
// CSR build (no degree sort) + single-pass fp16 edge-stream permute +
// merged weight prep; per layer: [MFMA dual GEMM (packed xlh + packed xrh),
// fused layer (1 wave/node, MFMA edge projection)].
// ---------------------------------------------------------------------------

typedef __attribute__((ext_vector_type(8))) short bf16x8;
typedef __attribute__((ext_vector_type(4))) float f32x4;
typedef __fp16 h2 __attribute__((ext_vector_type(2)));
typedef __fp16 h8 __attribute__((ext_vector_type(8)));

__device__ inline ushort f2bf(float f) {
  unsigned u = __float_as_uint(f);
  u += 0x7FFF + ((u >> 16) & 1);
  return (ushort)(u >> 16);
}

__device__ inline ushort f2h(float f) {
  __half h = __float2half(f);
  return *(ushort*)&h;
}

__device__ inline uint pk2(float a, float b) {
#if __has_builtin(__builtin_amdgcn_cvt_pkrtz)
  h2 r = __builtin_amdgcn_cvt_pkrtz(a, b);
  return *(uint*)&r;
#else
  return (uint)f2h(a) | ((uint)f2h(b) << 16);
#endif
}

__device__ inline uint swz_add(uint p, int o) {  // packed-f16 butterfly step
  int q = __shfl_xor(*(int*)&p, o);
  __half2 r = __hadd2(*(__half2*)&p, *(__half2*)&q);
  return *(uint*)&r;
}

// ---------------- CSR build ----------------

__global__ __launch_bounds__(256) void hist_kernel(const int* __restrict__ dst,
                                                   int* __restrict__ deg, int nE) {
  int i = blockIdx.x * 256 + threadIdx.x;
  if (i < nE) atomicAdd(&deg[dst[i]], 1);
}

__global__ __launch_bounds__(1024) void scan_blocks(const int* __restrict__ deg,
                                                    int* __restrict__ rowptr,
                                                    int* __restrict__ bsum, int n) {
  __shared__ int wsum[16];
  __shared__ int wbase[16];
  int tid = threadIdx.x, wid = tid >> 6, lane = tid & 63;
  int i = blockIdx.x * 1024 + tid;
  int v = (i < n) ? deg[i] : 0;
#pragma unroll
  for (int o = 1; o < 64; o <<= 1) {
    int t = __shfl_up(v, o);
    if (lane >= o) v += t;
  }
  if (lane == 63) wsum[wid] = v;
  __syncthreads();
  if (tid < 16) {
    int s = wsum[tid];
#pragma unroll
    for (int o = 1; o < 16; o <<= 1) {
      int t = __shfl_up(s, o);
      if (tid >= o) s += t;
    }
    wbase[tid] = s;
  }
  __syncthreads();
  int base = (wid > 0) ? wbase[wid - 1] : 0;
  if (i < n) rowptr[i + 1] = base + v;
  if (tid == 1023) bsum[blockIdx.x] = wbase[15];
}

__global__ __launch_bounds__(64) void scan_carry(int* __restrict__ bsum, int nb) {
  int lane = threadIdx.x;
  int carry = 0;
  for (int base = 0; base < nb; base += 64) {
    int i = base + lane;
    int v = (i < nb) ? bsum[i] : 0;
    int inc = v;
#pragma unroll
    for (int o = 1; o < 64; o <<= 1) {
      int t = __shfl_up(inc, o);
      if (lane >= o) inc += t;
    }
    if (i < nb) bsum[i] = carry + inc - v;
    carry += __shfl(inc, 63);
  }
}

__global__ __launch_bounds__(1024) void scan_apply(int* __restrict__ rowptr,
                                                   const int* __restrict__ bsum, int n) {
  int i = blockIdx.x * 1024 + threadIdx.x;
  if (i < n) rowptr[i + 1] += bsum[blockIdx.x];
  if (i == 0) rowptr[0] = 0;
}

__global__ __launch_bounds__(256) void scatter_kernel(const int* __restrict__ dst,
                                                      const int* __restrict__ rowptr,
                                                      int* __restrict__ cnt,
                                                      int* __restrict__ eperm, int nE) {
  int i = blockIdx.x * 256 + threadIdx.x;
  if (i < nE) {
    int d = dst[i];
    int p = atomicAdd(&cnt[d], 1);
    eperm[rowptr[d] + p] = i;
  }
}

// ---------------- edge stream prep (single pass) ----------------
// ea16[j] = fp16(ea[eperm[j]]) packed, src_perm[j] = src[eperm[j]].
// 8 threads per row: random fp32 reads are full-128B-granule, writes coalesced.
__global__ __launch_bounds__(256) void prep_edges_h(const float* __restrict__ ea,
                                                    const int* __restrict__ eperm,
                                                    const int* __restrict__ src,
                                                    ushort* __restrict__ ea16,
                                                    int* __restrict__ src_perm, int nE) {
  int t = blockIdx.x * 256 + threadIdx.x;
  int j = t >> 3, ch = (t & 7) << 2;
  if (j < nE) {
    int e = eperm[j];
    float4 v = *(const float4*)&ea[(size_t)e * 32 + ch];
    ushort4 h;
    h.x = f2h(v.x); h.y = f2h(v.y); h.z = f2h(v.z); h.w = f2h(v.w);
    *(ushort4*)&ea16[(size_t)j * 32 + ch] = h;
    if (ch == 0) src_perm[j] = src[e];
  }
}

// ---------------- weight prep ----------------

__global__ __launch_bounds__(256) void convert_x(const float* __restrict__ x,
                                                 ushort* __restrict__ xb, int n8) {
  int i = blockIdx.x * 256 + threadIdx.x;
  if (i < n8) {
    float4 a = ((const float4*)x)[i * 2];
    float4 b = ((const float4*)x)[i * 2 + 1];
    union { ushort r[8]; uint4 v; } u;
    u.r[0] = f2bf(a.x); u.r[1] = f2bf(a.y); u.r[2] = f2bf(a.z); u.r[3] = f2bf(a.w);
    u.r[4] = f2bf(b.x); u.r[5] = f2bf(b.y); u.r[6] = f2bf(b.z); u.r[7] = f2bf(b.w);
    ((uint4*)xb)[i] = u.v;
  }
}

// per layer: wt1/wt2 = bf16(W^T) [16384 each], weh = fp16(We^T) [4096]
__global__ __launch_bounds__(256) void prep_weights(
    const float* __restrict__ Wl0, const float* __restrict__ Wr0,
    const float* __restrict__ We0, const float* __restrict__ Wl1,
    const float* __restrict__ Wr1, const float* __restrict__ We1,
    const float* __restrict__ Wl2, const float* __restrict__ Wr2,
    const float* __restrict__ We2, ushort* __restrict__ wt1,
    ushort* __restrict__ wt2, ushort* __restrict__ weh) {
  int idx = blockIdx.x * 256 + threadIdx.x;
  int l = idx / 36864, rem = idx % 36864;
  if (l >= 3) return;
  const float* Wl = (l == 0) ? Wl0 : (l == 1) ? Wl1 : Wl2;
  const float* Wr = (l == 0) ? Wr0 : (l == 1) ? Wr1 : Wr2;
  const float* We = (l == 0) ? We0 : (l == 1) ? We1 : We2;
  if (rem < 16384) {
    int n = rem >> 7, k = rem & 127;
    wt1[l * 16384 + n * 128 + k] = f2bf(Wl[(size_t)k * 128 + n]);
  } else if (rem < 32768) {
    int r2 = rem - 16384;
    int n = r2 >> 7, k = r2 & 127;
    wt2[l * 16384 + n * 128 + k] = f2bf(Wr[(size_t)k * 128 + n]);
  } else {
    int r2 = rem - 32768;
    int n = r2 >> 5, k = r2 & 31;
    weh[l * 4096 + n * 32 + k] = f2h(We[(size_t)k * 128 + n]);
  }
}

// ---------------- MFMA dual GEMM ----------------
// 8 waves/block; wave owns 16 rows x ALL 128 cols. A-frags direct from
// global; W staged in ONE LDS buffer per matrix. Both outputs written as
// packed fp16 pairs (c, c+64) -- full-density coalesced dword stores.
#define XPAD 136

__device__ inline bf16x8 load_frag_g(const ushort* p) {
  union { bf16x8 v; unsigned long long q[2]; } u;
  u.q[0] = *(const unsigned long long*)p;
  u.q[1] = *(const unsigned long long*)(p + 16);
  return u.v;
}

__global__ __launch_bounds__(512) void gemm_mfma_dual(
    const ushort* __restrict__ xb, const ushort* __restrict__ wt1,
    const ushort* __restrict__ wt2, const float* __restrict__ b1,
    const float* __restrict__ b2, ushort* __restrict__ xlh,
    ushort* __restrict__ xrh, int nrows) {
  __shared__ ushort Ws[128 * XPAD];
  const int tid = threadIdx.x;
  const int wid = tid >> 6, lane = tid & 63;
  const int lr = lane & 15, lg = lane >> 4;
  const int r0 = blockIdx.x * 128;
  const int rw = r0 + wid * 16;

  bf16x8 afr[4];
  const int arow = min(rw + lr, nrows - 1);
#pragma unroll
  for (int ks = 0; ks < 4; ++ks) {
    afr[ks] = load_frag_g(&xb[(size_t)arow * 128 + ks * 32 + lg * 4]);
  }

#pragma unroll
  for (int m = 0; m < 2; ++m) {
    const ushort* wt = m ? wt2 : wt1;
    const float* bb = m ? b2 : b1;
    uint* __restrict__ outw = (uint*)(m ? xrh : xlh);
    __syncthreads();
#pragma unroll
    for (int i = 0; i < 4; ++i) {
      int c = tid + i * 512;
      int row = c >> 4, kc = (c & 15) << 3;
      *(uint4*)&Ws[row * XPAD + kc] = *(const uint4*)&wt[row * 128 + kc];
    }
    __syncthreads();

    f32x4 acc[8];
#pragma unroll
    for (int nt = 0; nt < 8; ++nt) acc[nt] = f32x4{0.f, 0.f, 0.f, 0.f};

#pragma unroll
    for (int ks = 0; ks < 4; ++ks) {
      const int kb = ks * 32 + lg * 4;
#pragma unroll
      for (int nt = 0; nt < 8; ++nt) {
        bf16x8 bw = load_frag_g(&Ws[(nt * 16 + lr) * XPAD + kb]);
        acc[nt] = __builtin_amdgcn_mfma_f32_16x16x32_bf16(afr[ks], bw, acc[nt], 0, 0, 0);
      }
    }

    // packed store: pair (c, c+64) = (nt*16+lr, (nt+4)*16+lr), nt<4
#pragma unroll
    for (int nt = 0; nt < 4; ++nt) {
      const float bbL = bb[nt * 16 + lr];
      const float bbH = bb[(nt + 4) * 16 + lr];
#pragma unroll
      for (int r = 0; r < 4; ++r) {
        int gr = rw + lg * 4 + r;
        if (gr < nrows) {
          outw[(size_t)gr * 64 + nt * 16 + lr] =
              pk2(acc[nt][r] + bbL, acc[nt + 4][r] + bbH);
        }
      }
    }
  }
}

// ---------------- fused GATv2 layer (MFMA edge projection) ----------------
// ONE wave per 64-thread block, node n = blockIdx.x (no sort). Per 16-edge
// tile: D[nt] = mfma_f32_16x16x32_f16(A=ea16 rows, We^T[nt]); lane holds
// rows 4*lg..+3 (reg r), col 16*nt+lr. Scores m = D + xr + xl; lrelu;
// att-dot; packed-f16 butterfly per 16-lane group; cross-group combine;
// softmax-normalize; LN; store.
template <int H, bool OB>
__global__ __launch_bounds__(64) void fused_gat(
    const ushort* __restrict__ xlh, const ushort* __restrict__ xrh,
    const ushort* __restrict__ ea16, const ushort* __restrict__ weh,
    const float* __restrict__ att, const int* __restrict__ rowptr,
    const int* __restrict__ src_perm, const float* __restrict__ bias,
    const float* __restrict__ gam, const float* __restrict__ bet,
    float* __restrict__ out, ushort* __restrict__ outb, int nN) {
  const int l = threadIdx.x;
  const int lr = l & 15, lg = l >> 4;
  const int n = blockIdx.x;
  const int rb = __builtin_amdgcn_readfirstlane(rowptr[n]);
  const int re = __builtin_amdgcn_readfirstlane(rowptr[n + 1]);
  const uint* __restrict__ xlw = (const uint*)xlh;
  const uint* __restrict__ xrw = (const uint*)xrh;

  unsigned long long bq[16];
#pragma unroll
  for (int nt = 0; nt < 8; ++nt) {
    const ushort* p = weh + (size_t)(nt * 16 + lr) * 32 + 4 * lg;
    bq[2 * nt] = *(const unsigned long long*)p;
    bq[2 * nt + 1] = *(const unsigned long long*)(p + 16);
  }

  float attv[8], xrv[8];
#pragma unroll
  for (int nt = 0; nt < 8; ++nt) attv[nt] = att[lr + 16 * nt] * 1.44269504f;
#pragma unroll
  for (int q = 0; q < 4; ++q) {
    uint u = xrw[(size_t)n * 64 + q * 16 + lr];
    float2 f = __half22float2(*(__half2*)&u);
    xrv[q] = f.x;
    xrv[q + 4] = f.y;
  }

  float acc[8] = {0.f, 0.f, 0.f, 0.f, 0.f, 0.f, 0.f, 0.f};
  float d0 = 0.f, d1 = 0.f, d2 = 0.f, d3 = 0.f;

  for (int t0 = rb; t0 < re; t0 += 16) {
    const int arow = min(t0 + lr, re - 1);
    union { unsigned long long q[2]; h8 v; } ua;
    const ushort* ap = ea16 + (size_t)arow * 32 + 4 * lg;
    ua.q[0] = *(const unsigned long long*)ap;
    ua.q[1] = *(const unsigned long long*)(ap + 16);

    int sr_[4];
#pragma unroll
    for (int r = 0; r < 4; ++r)
      sr_[r] = src_perm[min(t0 + 4 * lg + r, re - 1)];
    uint u[4][4];
#pragma unroll
    for (int r = 0; r < 4; ++r) {
      const uint* xp = xlw + (size_t)sr_[r] * 64;
#pragma unroll
      for (int q = 0; q < 4; ++q) u[r][q] = xp[lr + 16 * q];
    }

    f32x4 D[8];
#pragma unroll
    for (int nt = 0; nt < 8; ++nt) {
      union { unsigned long long q[2]; h8 v; } ub;
      ub.q[0] = bq[2 * nt];
      ub.q[1] = bq[2 * nt + 1];
      f32x4 z = {0.f, 0.f, 0.f, 0.f};
      D[nt] = __builtin_amdgcn_mfma_f32_16x16x32_f16(ua.v, ub.v, z, 0, 0, 0);
    }

    if (H == 4) {
#pragma unroll
      for (int r = 0; r < 4; ++r) {
        float xv[8];
#pragma unroll
        for (int q = 0; q < 4; ++q) {
          float2 f = __half22float2(*(__half2*)&u[r][q]);
          xv[q] = f.x;
          xv[q + 4] = f.y;
        }
        float p0 = 0.f, p1 = 0.f, p2 = 0.f, p3 = 0.f;
#pragma unroll
        for (int nt = 0; nt < 8; ++nt) {
          float m = D[nt][r] + xrv[nt] + xv[nt];
          m = fmaxf(m, 0.2f * m);
          float pm = m * attv[nt];
          if (nt < 2) p0 += pm;
          else if (nt < 4) p1 += pm;
          else if (nt < 6) p2 += pm;
          else p3 += pm;
        }
        uint pa = pk2(p0, p1), pb = pk2(p2, p3);
#pragma unroll
        for (int o = 1; o <= 8; o <<= 1) {
          pa = swz_add(pa, o);
          pb = swz_add(pb, o);
        }
        float2 sA = __half22float2(*(__half2*)&pa);
        float2 sB = __half22float2(*(__half2*)&pb);
        float w0 = exp2f(fminf(sA.x, 115.f));
        float w1 = exp2f(fminf(sA.y, 115.f));
        float w2 = exp2f(fminf(sB.x, 115.f));
        float w3 = exp2f(fminf(sB.y, 115.f));
        if (t0 + 4 * lg + r >= re) { w0 = 0.f; w1 = 0.f; w2 = 0.f; w3 = 0.f; }
        d0 += w0; d1 += w1; d2 += w2; d3 += w3;
#pragma unroll
        for (int nt = 0; nt < 8; ++nt) {
          float wn = (nt < 2) ? w0 : (nt < 4) ? w1 : (nt < 6) ? w2 : w3;
          acc[nt] += wn * xv[nt];
        }
      }
    } else {
#pragma unroll
      for (int rp = 0; rp < 2; ++rp) {
        const int ra = 2 * rp, rbx = 2 * rp + 1;
        float xva[8], xvb[8];
#pragma unroll
        for (int q = 0; q < 4; ++q) {
          float2 fa = __half22float2(*(__half2*)&u[ra][q]);
          float2 fb = __half22float2(*(__half2*)&u[rbx][q]);
          xva[q] = fa.x; xva[q + 4] = fa.y;
          xvb[q] = fb.x; xvb[q + 4] = fb.y;
        }
        float pA = 0.f, pB = 0.f;
#pragma unroll
        for (int nt = 0; nt < 8; ++nt) {
          float ma = D[nt][ra] + xrv[nt] + xva[nt];
          float mb = D[nt][rbx] + xrv[nt] + xvb[nt];
          ma = fmaxf(ma, 0.2f * ma);
          mb = fmaxf(mb, 0.2f * mb);
          pA += ma * attv[nt];
          pB += mb * attv[nt];
        }
        uint pa = pk2(pA, pB);
#pragma unroll
        for (int o = 1; o <= 8; o <<= 1) pa = swz_add(pa, o);
        float2 s = __half22float2(*(__half2*)&pa);
        float w0 = exp2f(fminf(s.x, 115.f));
        float w1 = exp2f(fminf(s.y, 115.f));
        if (t0 + 4 * lg + ra >= re) w0 = 0.f;
        if (t0 + 4 * lg + rbx >= re) w1 = 0.f;
        d0 += w0 + w1;
#pragma unroll
        for (int nt = 0; nt < 8; ++nt) acc[nt] += w0 * xva[nt] + w1 * xvb[nt];
      }
    }
  }

#pragma unroll
  for (int o = 16; o <= 32; o <<= 1) {
#pragma unroll
    for (int nt = 0; nt < 8; ++nt) acc[nt] += __shfl_xor(acc[nt], o);
    d0 += __shfl_xor(d0, o);
    if (H == 4) {
      d1 += __shfl_xor(d1, o);
      d2 += __shfl_xor(d2, o);
      d3 += __shfl_xor(d3, o);
    }
  }

  const float rd0 = (d0 > 0.f) ? 1.f / d0 : 0.f;
  const float rd1 = (H == 4) ? ((d1 > 0.f) ? 1.f / d1 : 0.f) : rd0;
  const float rd2 = (H == 4) ? ((d2 > 0.f) ? 1.f / d2 : 0.f) : rd0;
  const float rd3 = (H == 4) ? ((d3 > 0.f) ? 1.f / d3 : 0.f) : rd0;

  float y[8];
  float s1 = 0.f, s2 = 0.f;
#pragma unroll
  for (int nt = 0; nt < 8; ++nt) {
    const int c = lr + 16 * nt;
    const float rdn =
        (H == 1) ? rd0 : ((nt < 2) ? rd0 : (nt < 4) ? rd1 : (nt < 6) ? rd2 : rd3);
    y[nt] = acc[nt] * rdn + bias[c];
    s1 += y[nt];
    s2 += y[nt] * y[nt];
  }
#pragma unroll
  for (int o = 1; o <= 8; o <<= 1) {
    s1 += __shfl_xor(s1, o);
    s2 += __shfl_xor(s2, o);
  }
  const float mu = s1 * (1.f / 128.f);
  const float var = s2 * (1.f / 128.f) - mu * mu;
  const float rstd = rsqrtf(var + 1e-5f);
  if (lg == 0) {
#pragma unroll
    for (int nt = 0; nt < 8; ++nt) {
      const int c = lr + 16 * nt;
      const float o0 = fmaxf((y[nt] - mu) * rstd * gam[c] + bet[c], 0.f);
      if (OB)
        outb[(size_t)n * 128 + c] = f2bf(o0);
      else
        out[(size_t)n * 128 + c] = o0;
    }
  }
}

extern "C" void kernel_launch(void* const* d_in, const int* in_sizes, int n_in,
                              void* d_out, int out_size, void* d_ws, size_t ws_size,
                              hipStream_t stream) {
  const float* x = (const float*)d_in[0];
  const float* ea = (const float*)d_in[1];
  const int* src = (const int*)d_in[2];
  const int* dst = (const int*)d_in[3];
  const int N = in_sizes[0] / 128;
  const int E = in_sizes[2];

  char* w = (char*)d_ws;
  auto alloc = [&](size_t bytes) {
    char* p = w;
    w += (bytes + 255) & ~(size_t)255;
    return p;
  };
  ushort* xlh = (ushort*)alloc((size_t)N * 128 * 2);
  ushort* xrh = (ushort*)alloc((size_t)N * 128 * 2);
  ushort* xb = (ushort*)alloc((size_t)N * 128 * 2);
  ushort* wt1 = (ushort*)alloc(3 * 16384 * 2);
  ushort* wt2 = (ushort*)alloc(3 * 16384 * 2);
  ushort* weh = (ushort*)alloc(3 * 4096 * 2);
  int* eperm = (int*)alloc((size_t)E * 4);
  int* rowptr = (int*)alloc((size_t)(N + 1) * 4);
  int* deg = (int*)alloc((size_t)N * 4);
  int* cnt = (int*)alloc((size_t)N * 4);
  int* bsum = (int*)alloc(1024 * 4);
  ushort* ea16 = (ushort*)alloc((size_t)E * 32 * 2);
  int* src_perm = (int*)alloc((size_t)E * 4);

  hipMemsetAsync(deg, 0, (size_t)N * 4, stream);
  hipMemsetAsync(cnt, 0, (size_t)N * 4, stream);
  hist_kernel<<<(E + 255) / 256, 256, 0, stream>>>(dst, deg, E);
  int nb = (N + 1023) / 1024;
  scan_blocks<<<nb, 1024, 0, stream>>>(deg, rowptr, bsum, N);
  scan_carry<<<1, 64, 0, stream>>>(bsum, nb);
  scan_apply<<<nb, 1024, 0, stream>>>(rowptr, bsum, N);
  scatter_kernel<<<(E + 255) / 256, 256, 0, stream>>>(dst, rowptr, cnt, eperm, E);

  prep_edges_h<<<((size_t)E * 8 + 255) / 256, 256, 0, stream>>>(ea, eperm, src,
                                                                ea16, src_perm, E);

  int n8 = N * 128 / 8;
  convert_x<<<(n8 + 255) / 256, 256, 0, stream>>>(x, xb, n8);

  prep_weights<<<(3 * 36864 + 255) / 256, 256, 0, stream>>>(
      (const float*)d_in[4], (const float*)d_in[6], (const float*)d_in[8],
      (const float*)d_in[13], (const float*)d_in[15], (const float*)d_in[17],
      (const float*)d_in[22], (const float*)d_in[24], (const float*)d_in[26],
      wt1, wt2, weh);

  for (int l = 0; l < 3; ++l) {
    int bi = 4 + 9 * l;
    const float* bl = (const float*)d_in[bi + 1];
    const float* br = (const float*)d_in[bi + 3];
    const float* att = (const float*)d_in[bi + 5];
    const float* bo = (const float*)d_in[bi + 6];
    const float* gg = (const float*)d_in[bi + 7];
    const float* be = (const float*)d_in[bi + 8];

    gemm_mfma_dual<<<(N + 127) / 128, 512, 0, stream>>>(
        xb, wt1 + l * 16384, wt2 + l * 16384, bl, br, xlh, xrh, N);
    if (l < 2) {
      fused_gat<4, true><<<N, 64, 0, stream>>>(xlh, xrh, ea16, weh + l * 4096, att,
                                               rowptr, src_perm, bo, gg, be,
                                               nullptr, xb, N);
    } else {
      fused_gat<1, false><<<N, 64, 0, stream>>>(xlh, xrh, ea16, weh + l * 4096, att,
                                                rowptr, src_perm, bo, gg, be,
                                                (float*)d_out, nullptr, N);
    }
  }
}

// Round 18
// 496.751 us; speedup vs baseline: 1.7709x; 1.0544x over previous
//
#include <hip/hip_runtime.h>
#include <hip/hip_fp16.h>

// ---------------------------------------------------------------------------
// GATv2 3-layer GNN encoder. N=50000 nodes, E=800000 edges, dims 128.
// CSR build with fused permute (scatter_fat: coalesced fp32->fp16 edge rows
// written directly to CSR position) + merged weight prep; per layer:
// [MFMA dual GEMM (packed fp16 xlh/xrh), fused layer (1 wave/node, MFMA
// edge projection)].
// ---------------------------------------------------------------------------

typedef __attribute__((ext_vector_type(8))) short bf16x8;
typedef __attribute__((ext_vector_type(4))) float f32x4;
typedef __fp16 h2 __attribute__((ext_vector_type(2)));
typedef __fp16 h8 __attribute__((ext_vector_type(8)));

__device__ inline ushort f2bf(float f) {
  unsigned u = __float_as_uint(f);
  u += 0x7FFF + ((u >> 16) & 1);
  return (ushort)(u >> 16);
}

__device__ inline ushort f2h(float f) {
  __half h = __float2half(f);
  return *(ushort*)&h;
}

__device__ inline uint pk2(float a, float b) {
#if __has_builtin(__builtin_amdgcn_cvt_pkrtz)
  h2 r = __builtin_amdgcn_cvt_pkrtz(a, b);
  return *(uint*)&r;
#else
  return (uint)f2h(a) | ((uint)f2h(b) << 16);
#endif
}

__device__ inline uint swz_add(uint p, int o) {  // packed-f16 butterfly step
  int q = __shfl_xor(*(int*)&p, o);
  __half2 r = __hadd2(*(__half2*)&p, *(__half2*)&q);
  return *(uint*)&r;
}

// ---------------- CSR build ----------------

__global__ __launch_bounds__(256) void hist_kernel(const int* __restrict__ dst,
                                                   int* __restrict__ deg, int nE) {
  int i = blockIdx.x * 256 + threadIdx.x;
  if (i < nE) atomicAdd(&deg[dst[i]], 1);
}

__global__ __launch_bounds__(1024) void scan_blocks(const int* __restrict__ deg,
                                                    int* __restrict__ rowptr,
                                                    int* __restrict__ bsum, int n) {
  __shared__ int wsum[16];
  __shared__ int wbase[16];
  int tid = threadIdx.x, wid = tid >> 6, lane = tid & 63;
  int i = blockIdx.x * 1024 + tid;
  int v = (i < n) ? deg[i] : 0;
#pragma unroll
  for (int o = 1; o < 64; o <<= 1) {
    int t = __shfl_up(v, o);
    if (lane >= o) v += t;
  }
  if (lane == 63) wsum[wid] = v;
  __syncthreads();
  if (tid < 16) {
    int s = wsum[tid];
#pragma unroll
    for (int o = 1; o < 16; o <<= 1) {
      int t = __shfl_up(s, o);
      if (tid >= o) s += t;
    }
    wbase[tid] = s;
  }
  __syncthreads();
  int base = (wid > 0) ? wbase[wid - 1] : 0;
  if (i < n) rowptr[i + 1] = base + v;
  if (tid == 1023) bsum[blockIdx.x] = wbase[15];
}

__global__ __launch_bounds__(64) void scan_carry(int* __restrict__ bsum, int nb) {
  int lane = threadIdx.x;
  int carry = 0;
  for (int base = 0; base < nb; base += 64) {
    int i = base + lane;
    int v = (i < nb) ? bsum[i] : 0;
    int inc = v;
#pragma unroll
    for (int o = 1; o < 64; o <<= 1) {
      int t = __shfl_up(inc, o);
      if (lane >= o) inc += t;
    }
    if (i < nb) bsum[i] = carry + inc - v;
    carry += __shfl(inc, 63);
  }
}

__global__ __launch_bounds__(1024) void scan_apply(int* __restrict__ rowptr,
                                                   const int* __restrict__ bsum, int n) {
  int i = blockIdx.x * 1024 + threadIdx.x;
  if (i < n) rowptr[i + 1] += bsum[blockIdx.x];
  if (i == 0) rowptr[0] = 0;
}

// scatter + fp16-convert + permute in one pass. 8 threads per edge:
// coalesced fp32 ea reads; leader lane takes CSR slot via atomic; fp16 row
// + src written directly to permuted position (random 64B writes).
__global__ __launch_bounds__(256) void scatter_fat(
    const int* __restrict__ dst, const int* __restrict__ src,
    const float* __restrict__ ea, const int* __restrict__ rowptr,
    int* __restrict__ cnt, ushort* __restrict__ ea16,
    int* __restrict__ src_perm, int nE) {
  int t = blockIdx.x * 256 + threadIdx.x;
  int i = t >> 3, ch = (t & 7) << 2;
  if (i >= nE) return;
  const int lane = threadIdx.x & 63;
  const int leader = lane & ~7;
  int p = 0;
  if ((lane & 7) == 0) {
    int d = dst[i];
    p = rowptr[d] + atomicAdd(&cnt[d], 1);
  }
  const int j = __shfl(p, leader);
  float4 v = *(const float4*)&ea[(size_t)i * 32 + ch];
  ushort4 h;
  h.x = f2h(v.x); h.y = f2h(v.y); h.z = f2h(v.z); h.w = f2h(v.w);
  *(ushort4*)&ea16[(size_t)j * 32 + ch] = h;
  if ((lane & 7) == 0) src_perm[j] = src[i];
}

// ---------------- weight prep ----------------

__global__ __launch_bounds__(256) void convert_x(const float* __restrict__ x,
                                                 ushort* __restrict__ xb, int n8) {
  int i = blockIdx.x * 256 + threadIdx.x;
  if (i < n8) {
    float4 a = ((const float4*)x)[i * 2];
    float4 b = ((const float4*)x)[i * 2 + 1];
    union { ushort r[8]; uint4 v; } u;
    u.r[0] = f2bf(a.x); u.r[1] = f2bf(a.y); u.r[2] = f2bf(a.z); u.r[3] = f2bf(a.w);
    u.r[4] = f2bf(b.x); u.r[5] = f2bf(b.y); u.r[6] = f2bf(b.z); u.r[7] = f2bf(b.w);
    ((uint4*)xb)[i] = u.v;
  }
}

// per layer: wt1/wt2 = bf16(W^T) [16384 each], weh = fp16(We^T) [4096]
__global__ __launch_bounds__(256) void prep_weights(
    const float* __restrict__ Wl0, const float* __restrict__ Wr0,
    const float* __restrict__ We0, const float* __restrict__ Wl1,
    const float* __restrict__ Wr1, const float* __restrict__ We1,
    const float* __restrict__ Wl2, const float* __restrict__ Wr2,
    const float* __restrict__ We2, ushort* __restrict__ wt1,
    ushort* __restrict__ wt2, ushort* __restrict__ weh) {
  int idx = blockIdx.x * 256 + threadIdx.x;
  int l = idx / 36864, rem = idx % 36864;
  if (l >= 3) return;
  const float* Wl = (l == 0) ? Wl0 : (l == 1) ? Wl1 : Wl2;
  const float* Wr = (l == 0) ? Wr0 : (l == 1) ? Wr1 : Wr2;
  const float* We = (l == 0) ? We0 : (l == 1) ? We1 : We2;
  if (rem < 16384) {
    int n = rem >> 7, k = rem & 127;
    wt1[l * 16384 + n * 128 + k] = f2bf(Wl[(size_t)k * 128 + n]);
  } else if (rem < 32768) {
    int r2 = rem - 16384;
    int n = r2 >> 7, k = r2 & 127;
    wt2[l * 16384 + n * 128 + k] = f2bf(Wr[(size_t)k * 128 + n]);
  } else {
    int r2 = rem - 32768;
    int n = r2 >> 5, k = r2 & 31;
    weh[l * 4096 + n * 32 + k] = f2h(We[(size_t)k * 128 + n]);
  }
}

// ---------------- MFMA dual GEMM ----------------
#define XPAD 136

__device__ inline bf16x8 load_frag_g(const ushort* p) {
  union { bf16x8 v; unsigned long long q[2]; } u;
  u.q[0] = *(const unsigned long long*)p;
  u.q[1] = *(const unsigned long long*)(p + 16);
  return u.v;
}

__global__ __launch_bounds__(512) void gemm_mfma_dual(
    const ushort* __restrict__ xb, const ushort* __restrict__ wt1,
    const ushort* __restrict__ wt2, const float* __restrict__ b1,
    const float* __restrict__ b2, ushort* __restrict__ xlh,
    ushort* __restrict__ xrh, int nrows) {
  __shared__ ushort Ws[128 * XPAD];
  const int tid = threadIdx.x;
  const int wid = tid >> 6, lane = tid & 63;
  const int lr = lane & 15, lg = lane >> 4;
  const int r0 = blockIdx.x * 128;
  const int rw = r0 + wid * 16;

  bf16x8 afr[4];
  const int arow = min(rw + lr, nrows - 1);
#pragma unroll
  for (int ks = 0; ks < 4; ++ks) {
    afr[ks] = load_frag_g(&xb[(size_t)arow * 128 + ks * 32 + lg * 4]);
  }

#pragma unroll
  for (int m = 0; m < 2; ++m) {
    const ushort* wt = m ? wt2 : wt1;
    const float* bb = m ? b2 : b1;
    uint* __restrict__ outw = (uint*)(m ? xrh : xlh);
    __syncthreads();
#pragma unroll
    for (int i = 0; i < 4; ++i) {
      int c = tid + i * 512;
      int row = c >> 4, kc = (c & 15) << 3;
      *(uint4*)&Ws[row * XPAD + kc] = *(const uint4*)&wt[row * 128 + kc];
    }
    __syncthreads();

    f32x4 acc[8];
#pragma unroll
    for (int nt = 0; nt < 8; ++nt) acc[nt] = f32x4{0.f, 0.f, 0.f, 0.f};

#pragma unroll
    for (int ks = 0; ks < 4; ++ks) {
      const int kb = ks * 32 + lg * 4;
#pragma unroll
      for (int nt = 0; nt < 8; ++nt) {
        bf16x8 bw = load_frag_g(&Ws[(nt * 16 + lr) * XPAD + kb]);
        acc[nt] = __builtin_amdgcn_mfma_f32_16x16x32_bf16(afr[ks], bw, acc[nt], 0, 0, 0);
      }
    }

#pragma unroll
    for (int nt = 0; nt < 4; ++nt) {
      const float bbL = bb[nt * 16 + lr];
      const float bbH = bb[(nt + 4) * 16 + lr];
#pragma unroll
      for (int r = 0; r < 4; ++r) {
        int gr = rw + lg * 4 + r;
        if (gr < nrows) {
          outw[(size_t)gr * 64 + nt * 16 + lr] =
              pk2(acc[nt][r] + bbL, acc[nt + 4][r] + bbH);
        }
      }
    }
  }
}

// ---------------- fused GATv2 layer (MFMA edge projection) ----------------
template <int H, bool OB>
__global__ __launch_bounds__(64) void fused_gat(
    const ushort* __restrict__ xlh, const ushort* __restrict__ xrh,
    const ushort* __restrict__ ea16, const ushort* __restrict__ weh,
    const float* __restrict__ att, const int* __restrict__ rowptr,
    const int* __restrict__ src_perm, const float* __restrict__ bias,
    const float* __restrict__ gam, const float* __restrict__ bet,
    float* __restrict__ out, ushort* __restrict__ outb, int nN) {
  const int l = threadIdx.x;
  const int lr = l & 15, lg = l >> 4;
  const int n = blockIdx.x;
  const int rb = __builtin_amdgcn_readfirstlane(rowptr[n]);
  const int re = __builtin_amdgcn_readfirstlane(rowptr[n + 1]);
  const uint* __restrict__ xlw = (const uint*)xlh;
  const uint* __restrict__ xrw = (const uint*)xrh;

  unsigned long long bq[16];
#pragma unroll
  for (int nt = 0; nt < 8; ++nt) {
    const ushort* p = weh + (size_t)(nt * 16 + lr) * 32 + 4 * lg;
    bq[2 * nt] = *(const unsigned long long*)p;
    bq[2 * nt + 1] = *(const unsigned long long*)(p + 16);
  }

  float attv[8], xrv[8];
#pragma unroll
  for (int nt = 0; nt < 8; ++nt) attv[nt] = att[lr + 16 * nt] * 1.44269504f;
#pragma unroll
  for (int q = 0; q < 4; ++q) {
    uint u = xrw[(size_t)n * 64 + q * 16 + lr];
    float2 f = __half22float2(*(__half2*)&u);
    xrv[q] = f.x;
    xrv[q + 4] = f.y;
  }

  float acc[8] = {0.f, 0.f, 0.f, 0.f, 0.f, 0.f, 0.f, 0.f};
  float d0 = 0.f, d1 = 0.f, d2 = 0.f, d3 = 0.f;

  for (int t0 = rb; t0 < re; t0 += 16) {
    const int arow = min(t0 + lr, re - 1);
    union { unsigned long long q[2]; h8 v; } ua;
    const ushort* ap = ea16 + (size_t)arow * 32 + 4 * lg;
    ua.q[0] = *(const unsigned long long*)ap;
    ua.q[1] = *(const unsigned long long*)(ap + 16);

    int sr_[4];
#pragma unroll
    for (int r = 0; r < 4; ++r)
      sr_[r] = src_perm[min(t0 + 4 * lg + r, re - 1)];
    uint u[4][4];
#pragma unroll
    for (int r = 0; r < 4; ++r) {
      const uint* xp = xlw + (size_t)sr_[r] * 64;
#pragma unroll
      for (int q = 0; q < 4; ++q) u[r][q] = xp[lr + 16 * q];
    }

    f32x4 D[8];
#pragma unroll
    for (int nt = 0; nt < 8; ++nt) {
      union { unsigned long long q[2]; h8 v; } ub;
      ub.q[0] = bq[2 * nt];
      ub.q[1] = bq[2 * nt + 1];
      f32x4 z = {0.f, 0.f, 0.f, 0.f};
      D[nt] = __builtin_amdgcn_mfma_f32_16x16x32_f16(ua.v, ub.v, z, 0, 0, 0);
    }

    if (H == 4) {
#pragma unroll
      for (int r = 0; r < 4; ++r) {
        float xv[8];
#pragma unroll
        for (int q = 0; q < 4; ++q) {
          float2 f = __half22float2(*(__half2*)&u[r][q]);
          xv[q] = f.x;
          xv[q + 4] = f.y;
        }
        float p0 = 0.f, p1 = 0.f, p2 = 0.f, p3 = 0.f;
#pragma unroll
        for (int nt = 0; nt < 8; ++nt) {
          float m = D[nt][r] + xrv[nt] + xv[nt];
          m = fmaxf(m, 0.2f * m);
          float pm = m * attv[nt];
          if (nt < 2) p0 += pm;
          else if (nt < 4) p1 += pm;
          else if (nt < 6) p2 += pm;
          else p3 += pm;
        }
        uint pa = pk2(p0, p1), pb = pk2(p2, p3);
#pragma unroll
        for (int o = 1; o <= 8; o <<= 1) {
          pa = swz_add(pa, o);
          pb = swz_add(pb, o);
        }
        float2 sA = __half22float2(*(__half2*)&pa);
        float2 sB = __half22float2(*(__half2*)&pb);
        float w0 = exp2f(fminf(sA.x, 115.f));
        float w1 = exp2f(fminf(sA.y, 115.f));
        float w2 = exp2f(fminf(sB.x, 115.f));
        float w3 = exp2f(fminf(sB.y, 115.f));
        if (t0 + 4 * lg + r >= re) { w0 = 0.f; w1 = 0.f; w2 = 0.f; w3 = 0.f; }
        d0 += w0; d1 += w1; d2 += w2; d3 += w3;
#pragma unroll
        for (int nt = 0; nt < 8; ++nt) {
          float wn = (nt < 2) ? w0 : (nt < 4) ? w1 : (nt < 6) ? w2 : w3;
          acc[nt] += wn * xv[nt];
        }
      }
    } else {
#pragma unroll
      for (int rp = 0; rp < 2; ++rp) {
        const int ra = 2 * rp, rbx = 2 * rp + 1;
        float xva[8], xvb[8];
#pragma unroll
        for (int q = 0; q < 4; ++q) {
          float2 fa = __half22float2(*(__half2*)&u[ra][q]);
          float2 fb = __half22float2(*(__half2*)&u[rbx][q]);
          xva[q] = fa.x; xva[q + 4] = fa.y;
          xvb[q] = fb.x; xvb[q + 4] = fb.y;
        }
        float pA = 0.f, pB = 0.f;
#pragma unroll
        for (int nt = 0; nt < 8; ++nt) {
          float ma = D[nt][ra] + xrv[nt] + xva[nt];
          float mb = D[nt][rbx] + xrv[nt] + xvb[nt];
          ma = fmaxf(ma, 0.2f * ma);
          mb = fmaxf(mb, 0.2f * mb);
          pA += ma * attv[nt];
          pB += mb * attv[nt];
        }
        uint pa = pk2(pA, pB);
#pragma unroll
        for (int o = 1; o <= 8; o <<= 1) pa = swz_add(pa, o);
        float2 s = __half22float2(*(__half2*)&pa);
        float w0 = exp2f(fminf(s.x, 115.f));
        float w1 = exp2f(fminf(s.y, 115.f));
        if (t0 + 4 * lg + ra >= re) w0 = 0.f;
        if (t0 + 4 * lg + rbx >= re) w1 = 0.f;
        d0 += w0 + w1;
#pragma unroll
        for (int nt = 0; nt < 8; ++nt) acc[nt] += w0 * xva[nt] + w1 * xvb[nt];
      }
    }
  }

#pragma unroll
  for (int o = 16; o <= 32; o <<= 1) {
#pragma unroll
    for (int nt = 0; nt < 8; ++nt) acc[nt] += __shfl_xor(acc[nt], o);
    d0 += __shfl_xor(d0, o);
    if (H == 4) {
      d1 += __shfl_xor(d1, o);
      d2 += __shfl_xor(d2, o);
      d3 += __shfl_xor(d3, o);
    }
  }

  const float rd0 = (d0 > 0.f) ? 1.f / d0 : 0.f;
  const float rd1 = (H == 4) ? ((d1 > 0.f) ? 1.f / d1 : 0.f) : rd0;
  const float rd2 = (H == 4) ? ((d2 > 0.f) ? 1.f / d2 : 0.f) : rd0;
  const float rd3 = (H == 4) ? ((d3 > 0.f) ? 1.f / d3 : 0.f) : rd0;

  float y[8];
  float s1 = 0.f, s2 = 0.f;
#pragma unroll
  for (int nt = 0; nt < 8; ++nt) {
    const int c = lr + 16 * nt;
    const float rdn =
        (H == 1) ? rd0 : ((nt < 2) ? rd0 : (nt < 4) ? rd1 : (nt < 6) ? rd2 : rd3);
    y[nt] = acc[nt] * rdn + bias[c];
    s1 += y[nt];
    s2 += y[nt] * y[nt];
  }
#pragma unroll
  for (int o = 1; o <= 8; o <<= 1) {
    s1 += __shfl_xor(s1, o);
    s2 += __shfl_xor(s2, o);
  }
  const float mu = s1 * (1.f / 128.f);
  const float var = s2 * (1.f / 128.f) - mu * mu;
  const float rstd = rsqrtf(var + 1e-5f);
  if (lg == 0) {
#pragma unroll
    for (int nt = 0; nt < 8; ++nt) {
      const int c = lr + 16 * nt;
      const float o0 = fmaxf((y[nt] - mu) * rstd * gam[c] + bet[c], 0.f);
      if (OB)
        outb[(size_t)n * 128 + c] = f2bf(o0);
      else
        out[(size_t)n * 128 + c] = o0;
    }
  }
}

extern "C" void kernel_launch(void* const* d_in, const int* in_sizes, int n_in,
                              void* d_out, int out_size, void* d_ws, size_t ws_size,
                              hipStream_t stream) {
  const float* x = (const float*)d_in[0];
  const float* ea = (const float*)d_in[1];
  const int* src = (const int*)d_in[2];
  const int* dst = (const int*)d_in[3];
  const int N = in_sizes[0] / 128;
  const int E = in_sizes[2];

  char* w = (char*)d_ws;
  auto alloc = [&](size_t bytes) {
    char* p = w;
    w += (bytes + 255) & ~(size_t)255;
    return p;
  };
  ushort* xlh = (ushort*)alloc((size_t)N * 128 * 2);
  ushort* xrh = (ushort*)alloc((size_t)N * 128 * 2);
  ushort* xb = (ushort*)alloc((size_t)N * 128 * 2);
  ushort* wt1 = (ushort*)alloc(3 * 16384 * 2);
  ushort* wt2 = (ushort*)alloc(3 * 16384 * 2);
  ushort* weh = (ushort*)alloc(3 * 4096 * 2);
  int* rowptr = (int*)alloc((size_t)(N + 1) * 4);
  int* deg = (int*)alloc((size_t)N * 4);
  int* cnt = (int*)alloc((size_t)N * 4);
  int* bsum = (int*)alloc(1024 * 4);
  ushort* ea16 = (ushort*)alloc((size_t)E * 32 * 2);
  int* src_perm = (int*)alloc((size_t)E * 4);

  hipMemsetAsync(deg, 0, (size_t)N * 4, stream);
  hipMemsetAsync(cnt, 0, (size_t)N * 4, stream);
  hist_kernel<<<(E + 255) / 256, 256, 0, stream>>>(dst, deg, E);
  int nb = (N + 1023) / 1024;
  scan_blocks<<<nb, 1024, 0, stream>>>(deg, rowptr, bsum, N);
  scan_carry<<<1, 64, 0, stream>>>(bsum, nb);
  scan_apply<<<nb, 1024, 0, stream>>>(rowptr, bsum, N);
  scatter_fat<<<((size_t)E * 8 + 255) / 256, 256, 0, stream>>>(
      dst, src, ea, rowptr, cnt, ea16, src_perm, E);

  int n8 = N * 128 / 8;
  convert_x<<<(n8 + 255) / 256, 256, 0, stream>>>(x, xb, n8);

  prep_weights<<<(3 * 36864 + 255) / 256, 256, 0, stream>>>(
      (const float*)d_in[4], (const float*)d_in[6], (const float*)d_in[8],
      (const float*)d_in[13], (const float*)d_in[15], (const float*)d_in[17],
      (const float*)d_in[22], (const float*)d_in[24], (const float*)d_in[26],
      wt1, wt2, weh);

  for (int l = 0; l < 3; ++l) {
    int bi = 4 + 9 * l;
    const float* bl = (const float*)d_in[bi + 1];
    const float* br = (const float*)d_in[bi + 3];
    const float* att = (const float*)d_in[bi + 5];
    const float* bo = (const float*)d_in[bi + 6];
    const float* gg = (const float*)d_in[bi + 7];
    const float* be = (const float*)d_in[bi + 8];

    gemm_mfma_dual<<<(N + 127) / 128, 512, 0, stream>>>(
        xb, wt1 + l * 16384, wt2 + l * 16384, bl, br, xlh, xrh, N);
    if (l < 2) {
      fused_gat<4, true><<<N, 64, 0, stream>>>(xlh, xrh, ea16, weh + l * 4096, att,
                                               rowptr, src_perm, bo, gg, be,
                                               nullptr, xb, N);
    } else {
      fused_gat<1, false><<<N, 64, 0, stream>>>(xlh, xrh, ea16, weh + l * 4096, att,
                                                rowptr, src_perm, bo, gg, be,
                                                (float*)d_out, nullptr, N);
    }
  }
}